// Round 2
// baseline (646.498 us; speedup 1.0000x reference)
//
#include <hip/hip_runtime.h>
#include <cstdint>
#include <cstddef>

// Shapes
// B=16, L=16384, E=16, H=128, NH=4, DH=32, FF=256, D_STATE=32, HEADDIM=32
// D_INNER=256, NHEADS=8, CONV_DIM=320, DCONV=4, LC=512, ROWS=B*LC=8192

#define EPI_NONE 0
#define EPI_BNGELU 1
#define EPI_QKV 2
#define EPI_RESBIAS 3
#define EPI_BIASGELU 4

static __device__ __forceinline__ float gelu_f(float x) {
  float t = tanhf(0.7978845608028654f * (x + 0.044715f * x * x * x));
  return 0.5f * x * (1.0f + t);
}

// ---------------- prep: effective conv weights, BN folding, qkv pack ----------------
__global__ __launch_bounds__(256) void prep_k(
    const float* __restrict__ w_in, const float* __restrict__ b_in,
    const float* __restrict__ c1w, const float* __restrict__ bn1g,
    const float* __restrict__ bn1b, const float* __restrict__ c2w,
    const float* __restrict__ bn2g, const float* __restrict__ bn2b,
    const float* __restrict__ wq, const float* __restrict__ wk,
    const float* __restrict__ wv,
    float* __restrict__ W1, float* __restrict__ W2,
    float* __restrict__ sc, float* __restrict__ Bqkv) {
  int idx = blockIdx.x * 256 + threadIdx.x;
  const float inv = rsqrtf(1.0f + 1e-5f);
  if (idx < 16384) {
    // W1eff[k=(i*16+e)][c] = sum_cin w_in[e,cin]*conv1_w[c,cin,i]
    int k = idx >> 7, c = idx & 127;
    int e = k & 15, i = k >> 4;
    float s = 0.f;
    #pragma unroll 4
    for (int cin = 0; cin < 128; ++cin)
      s += w_in[e * 128 + cin] * c1w[c * 1024 + cin * 8 + i];
    W1[idx] = s;
  } else if (idx < 16384 + 65536) {
    // W2eff[k=(i*128+cin)][c] = conv2_w[c,cin,i]
    int j = idx - 16384;
    int k = j >> 7, c = j & 127;
    int i = k >> 7, cin = k & 127;
    W2[j] = c2w[c * 512 + cin * 4 + i];
  } else if (idx < 16384 + 65536 + 128) {
    int c = idx - (16384 + 65536);
    float b1 = 0.f;
    for (int cin = 0; cin < 128; ++cin) {
      float bi = b_in[cin];
      #pragma unroll
      for (int i = 0; i < 8; ++i) b1 += bi * c1w[c * 1024 + cin * 8 + i];
    }
    float s1 = bn1g[c] * inv;
    sc[c] = s1;                       // scale1
    sc[128 + c] = b1 * s1 + bn1b[c];  // shift1 (conv bias folded)
    sc[256 + c] = bn2g[c] * inv;      // scale2
    sc[384 + c] = bn2b[c];            // shift2
  } else {
    int j = idx - (16384 + 65536 + 128);
    if (j < 128 * 384) {
      int k = j / 384, n = j % 384;
      float v = (n < 128) ? wq[k * 128 + n]
              : (n < 256) ? wk[k * 128 + (n - 128)]
                          : wv[k * 128 + (n - 256)];
      Bqkv[j] = v;
    }
  }
}

// ---------------- generic fp32 GEMM, row-major, BM x 128 x BK=32, 256 thr ----------------
// BM in {32, 64}. RT = BM/8 rows per thread. grid.x = M/BM, grid.y = ceil(N/128).
template <int EPI, int BM>
__global__ __launch_bounds__(256) void gemm_k(
    const float* __restrict__ A, const float* __restrict__ B,
    float* __restrict__ C, const float* __restrict__ Cres,
    const float* __restrict__ v0, const float* __restrict__ v1,
    int M, int N, int K) {
  constexpr int RT = BM / 8;
  __shared__ float As[BM][33];   // [m][k], pad 1: broadcast reads, conflict-free writes
  __shared__ float Bs[32][128];  // [k][n], float4 both sides
  const int tid = threadIdx.x;
  const int row0 = blockIdx.x * BM;
  const int n0 = blockIdx.y * 128;
  const int tr = tid >> 5, tc = tid & 31;
  float acc[RT][4];
  #pragma unroll
  for (int i = 0; i < RT; ++i)
    for (int j = 0; j < 4; ++j) acc[i][j] = 0.f;

  for (int k0 = 0; k0 < K; k0 += 32) {
    #pragma unroll
    for (int i = 0; i < BM / 32; ++i) {
      int j = i * 256 + tid;                 // BM*8 float4s of A tile
      int m = j >> 3, k4 = (j & 7) << 2;
      const float4 av = *(const float4*)(A + (size_t)(row0 + m) * K + k0 + k4);
      As[m][k4] = av.x; As[m][k4 + 1] = av.y; As[m][k4 + 2] = av.z; As[m][k4 + 3] = av.w;
    }
    #pragma unroll
    for (int i = 0; i < 4; ++i) {
      int j = i * 256 + tid;                 // 1024 float4s of B tile
      int kk = j >> 5, c4 = (j & 31) << 2;
      float4 bv = make_float4(0.f, 0.f, 0.f, 0.f);
      if (n0 + c4 < N) bv = *(const float4*)(B + (size_t)(k0 + kk) * N + n0 + c4);
      *(float4*)&Bs[kk][c4] = bv;
    }
    __syncthreads();
    #pragma unroll
    for (int kk = 0; kk < 32; ++kk) {
      const float4 bv = *(const float4*)&Bs[kk][tc << 2];
      #pragma unroll
      for (int i = 0; i < RT; ++i) {
        float a = As[tr * RT + i][kk];
        acc[i][0] = fmaf(a, bv.x, acc[i][0]);
        acc[i][1] = fmaf(a, bv.y, acc[i][1]);
        acc[i][2] = fmaf(a, bv.z, acc[i][2]);
        acc[i][3] = fmaf(a, bv.w, acc[i][3]);
      }
    }
    __syncthreads();
  }

  int cc = n0 + (tc << 2);
  if (cc >= N) return;
  #pragma unroll
  for (int i = 0; i < RT; ++i) {
    int rr = row0 + tr * RT + i;
    float o[4];
    #pragma unroll
    for (int jj = 0; jj < 4; ++jj) {
      float x = acc[i][jj];
      if (EPI == EPI_BNGELU) x = gelu_f(x * v0[cc + jj] + v1[cc + jj]);
      else if (EPI == EPI_QKV) { if (cc + jj < 256) x = (x > 0.f) ? x + 1.f : __expf(x); }
      else if (EPI == EPI_RESBIAS) x = Cres[(size_t)rr * N + cc + jj] + x + v0[cc + jj];
      else if (EPI == EPI_BIASGELU) x = gelu_f(x + v0[cc + jj]);
      o[jj] = x;
    }
    *(float4*)(C + (size_t)rr * N + cc) = make_float4(o[0], o[1], o[2], o[3]);
  }
}

// ---------------- LayerNorm over 128, one wave per row ----------------
__global__ __launch_bounds__(256) void ln_rows_k(
    const float* __restrict__ in, float* __restrict__ out,
    const float* __restrict__ g, const float* __restrict__ b) {
  int r = (blockIdx.x << 2) + (threadIdx.x >> 6);
  int lane = threadIdx.x & 63;
  size_t base = (size_t)r * 128 + lane * 2;
  float2 v = *(const float2*)(in + base);
  float s = v.x + v.y, q = v.x * v.x + v.y * v.y;
  #pragma unroll
  for (int off = 1; off < 64; off <<= 1) {
    s += __shfl_xor(s, off);
    q += __shfl_xor(q, off);
  }
  float m = s * (1.f / 128.f);
  float var = q * (1.f / 128.f) - m * m;
  float rs = rsqrtf(var + 1e-5f);
  float2 gg = *(const float2*)(g + lane * 2);
  float2 bb = *(const float2*)(b + lane * 2);
  float2 o;
  o.x = (v.x - m) * rs * gg.x + bb.x;
  o.y = (v.y - m) * rs * gg.y + bb.y;
  *(float2*)(out + base) = o;
}

// ---------------- linear-attn: kv[b,h,d,e] and ksum[b,h,d] ----------------
__global__ __launch_bounds__(256) void attn_kv_k(
    const float* __restrict__ qkv, float* __restrict__ kv, float* __restrict__ ksum) {
  int bh = blockIdx.x;  // b*4+h
  int b = bh >> 2, h = bh & 3;
  int t = threadIdx.x;
  int d = t >> 3, e4 = (t & 7) << 2;
  __shared__ float ks[8][32], vs[8][32];
  float a0 = 0, a1 = 0, a2 = 0, a3 = 0, ksa = 0;
  size_t base = (size_t)b * 512 * 384;
  for (int lc = 0; lc < 512; lc += 8) {
    #pragma unroll
    for (int i = 0; i < 2; ++i) {
      int j = i * 256 + t;  // 512 values: 8 rows x (k[32] | v[32])
      int rl = j >> 6, rem = j & 63, half = rem >> 5, col = rem & 31;
      float val = qkv[base + (size_t)(lc + rl) * 384 + 128 + half * 128 + h * 32 + col];
      if (half) vs[rl][col] = val; else ks[rl][col] = val;
    }
    __syncthreads();
    #pragma unroll
    for (int r = 0; r < 8; ++r) {
      float kd = ks[r][d];
      if ((t & 7) == 0) ksa += kd;
      a0 = fmaf(kd, vs[r][e4 + 0], a0);
      a1 = fmaf(kd, vs[r][e4 + 1], a1);
      a2 = fmaf(kd, vs[r][e4 + 2], a2);
      a3 = fmaf(kd, vs[r][e4 + 3], a3);
    }
    __syncthreads();
  }
  float* kvp = kv + (size_t)bh * 1024 + d * 32 + e4;
  kvp[0] = a0; kvp[1] = a1; kvp[2] = a2; kvp[3] = a3;
  if ((t & 7) == 0) ksum[bh * 32 + d] = ksa;
}

// ---------------- linear-attn apply: attn = (q@kv) / (q.ksum + 1e-6) ----------------
__global__ __launch_bounds__(128) void attn_apply_k(
    const float* __restrict__ qkv, const float* __restrict__ kv,
    const float* __restrict__ ksum, float* __restrict__ attn) {
  int row = blockIdx.x;
  int t = threadIdx.x, h = t >> 5, e = t & 31;
  int b = row >> 9;
  const float* qr = qkv + (size_t)row * 384 + h * 32;
  const float* kvp = kv + (size_t)(b * 4 + h) * 1024;
  const float* ksp = ksum + (b * 4 + h) * 32;
  float num = 0.f, den = 0.f;
  #pragma unroll 8
  for (int d = 0; d < 32; ++d) {
    float qd = qr[d];
    num = fmaf(qd, kvp[d * 32 + e], num);
    den = fmaf(qd, ksp[d], den);
  }
  attn[(size_t)row * 128 + t] = num / (den + 1e-6f);
}

// ---------------- mamba depthwise causal conv (DCONV=4) + silu; dt softplus ----------------
__global__ __launch_bounds__(320) void mamba_conv_k(
    const float* __restrict__ zx, const float* __restrict__ cw,
    const float* __restrict__ cb, const float* __restrict__ dtb,
    float* __restrict__ xc, float* __restrict__ dt) {
  int row = blockIdx.x;  // b*512 + l
  int c = threadIdx.x;   // 0..319
  int l = row & 511;
  float acc = cb[c];
  #pragma unroll
  for (int i = 0; i < 4; ++i) {
    int dl = i - 3;
    if (l + dl >= 0)
      acc += zx[(size_t)(row + dl) * 584 + 256 + c] * cw[c * 4 + i];
  }
  float s = acc / (1.f + __expf(-acc));  // silu
  xc[(size_t)row * 320 + c] = s;
  if (c < 8) {
    float r = zx[(size_t)row * 584 + 576 + c] + dtb[c];
    dt[(size_t)row * 8 + c] = fmaxf(r, 0.f) + log1pf(__expf(-fabsf(r)));  // softplus
  }
}

// ---------------- SSM scan: one block per (b,head), state in registers ----------------
__global__ __launch_bounds__(1024) void scan_k(
    const float* __restrict__ xc, const float* __restrict__ dt,
    const float* __restrict__ A_log, const float* __restrict__ Dsk,
    float* __restrict__ y) {
  int bh = blockIdx.x;  // b*8 + h
  int b = bh >> 3, h = bh & 7;
  int t = threadIdx.x;
  int p = t >> 5, n = t & 31;
  float Ah = -__expf(A_log[h]);
  float Dh = Dsk[h];
  float hst = 0.f;
  size_t rbase = (size_t)b * 512;
  for (int l = 0; l < 512; ++l) {
    size_t row = rbase + l;
    float dtv = dt[row * 8 + h];
    float da = __expf(dtv * Ah);
    const float* xr = xc + row * 320;
    float bm = xr[256 + n];
    float cm = xr[288 + n];
    float xs = xr[h * 32 + p];
    hst = fmaf(hst, da, dtv * bm * xs);
    float pr = hst * cm;
    #pragma unroll
    for (int off = 16; off; off >>= 1) pr += __shfl_xor(pr, off);
    if (n == 0) y[row * 256 + h * 32 + p] = pr + Dh * xs;
  }
}

// ---------------- y gating: y *= silu(zg); RMS(256) * mnorm_w ----------------
__global__ __launch_bounds__(256) void gate_rms_k(
    float* __restrict__ y, const float* __restrict__ zx, const float* __restrict__ mw) {
  int row = blockIdx.x;
  int c = threadIdx.x;
  float zg = zx[(size_t)row * 584 + c];
  float val = y[(size_t)row * 256 + c] * (zg / (1.f + __expf(-zg)));
  float sq = val * val;
  #pragma unroll
  for (int off = 1; off < 64; off <<= 1) sq += __shfl_xor(sq, off);
  __shared__ float ps[4];
  if ((c & 63) == 0) ps[c >> 6] = sq;
  __syncthreads();
  float tot = ps[0] + ps[1] + ps[2] + ps[3];
  y[(size_t)row * 256 + c] = val * rsqrtf(tot * (1.f / 256.f) + 1e-6f) * mw[c];
}

// ---------------- final: RMS(t + residual) then LN ----------------
__global__ __launch_bounds__(256) void final_k(
    const float* __restrict__ t, const float* __restrict__ hres,
    const float* __restrict__ rmsw, const float* __restrict__ g,
    const float* __restrict__ b, float* __restrict__ out) {
  int r = (blockIdx.x << 2) + (threadIdx.x >> 6);
  int lane = threadIdx.x & 63;
  size_t base = (size_t)r * 128 + lane * 2;
  float2 tv = *(const float2*)(t + base);
  float2 hv = *(const float2*)(hres + base);
  float vx = tv.x + hv.x, vy = tv.y + hv.y;
  float sq = vx * vx + vy * vy;
  #pragma unroll
  for (int off = 1; off < 64; off <<= 1) sq += __shfl_xor(sq, off);
  float rs = rsqrtf(sq * (1.f / 128.f) + 1e-6f);
  float rx = vx * rs * rmsw[lane * 2], ry = vy * rs * rmsw[lane * 2 + 1];
  float s = rx + ry, q2 = rx * rx + ry * ry;
  #pragma unroll
  for (int off = 1; off < 64; off <<= 1) {
    s += __shfl_xor(s, off);
    q2 += __shfl_xor(q2, off);
  }
  float m = s * (1.f / 128.f), var = q2 * (1.f / 128.f) - m * m;
  float inv = rsqrtf(var + 1e-5f);
  float2 o;
  o.x = (rx - m) * inv * g[lane * 2] + b[lane * 2];
  o.y = (ry - m) * inv * g[lane * 2 + 1] + b[lane * 2 + 1];
  *(float2*)(out + base) = o;
}

extern "C" void kernel_launch(void* const* d_in, const int* in_sizes, int n_in,
                              void* d_out, int out_size, void* d_ws, size_t ws_size,
                              hipStream_t stream) {
  const float* x      = (const float*)d_in[0];
  const float* w_in   = (const float*)d_in[1];
  const float* b_in   = (const float*)d_in[2];
  const float* c1w    = (const float*)d_in[3];
  const float* bn1g   = (const float*)d_in[4];
  const float* bn1b   = (const float*)d_in[5];
  const float* c2w    = (const float*)d_in[6];
  const float* bn2g   = (const float*)d_in[7];
  const float* bn2b   = (const float*)d_in[8];
  const float* ln1g   = (const float*)d_in[9];
  const float* ln1b   = (const float*)d_in[10];
  const float* wq     = (const float*)d_in[11];
  const float* wk     = (const float*)d_in[12];
  const float* wv     = (const float*)d_in[13];
  const float* wo     = (const float*)d_in[14];
  const float* bo     = (const float*)d_in[15];
  const float* ln2g   = (const float*)d_in[16];
  const float* ln2b   = (const float*)d_in[17];
  const float* ff1w   = (const float*)d_in[18];
  const float* ff1b   = (const float*)d_in[19];
  const float* ff2w   = (const float*)d_in[20];
  const float* ff2b   = (const float*)d_in[21];
  const float* ipw    = (const float*)d_in[22];
  const float* cw     = (const float*)d_in[23];
  const float* cb     = (const float*)d_in[24];
  const float* dtb    = (const float*)d_in[25];
  const float* Alog   = (const float*)d_in[26];
  const float* Dsk    = (const float*)d_in[27];
  const float* mnw    = (const float*)d_in[28];
  const float* outw   = (const float*)d_in[29];
  const float* rmsw   = (const float*)d_in[30];
  const float* olng   = (const float*)d_in[31];
  const float* olnb   = (const float*)d_in[32];

  float* ws = (float*)d_ws;
  const size_t MG = 1u << 20;
  // small region (< 1M floats)
  float* W1   = ws + 0;        // 16384
  float* W2   = ws + 16384;    // 65536
  float* SC   = ws + 81920;    // 512
  float* BQKV = ws + 82432;    // 49152
  float* KV   = ws + 131584;   // 65536
  float* KS   = ws + 197120;   // 2048
  float* DT   = ws + 199168;   // 65536
  // big region R at 1M..~7M, time-multiplexed
  float* R    = ws + MG;
  float* OUT1 = R;             // 4M floats   (gemm1 -> gemm2)
  float* QKV  = R;             // 3M floats   (qkv -> attn)
  float* ATTN = R + 3 * MG;    // 1M floats
  float* MID  = R;             // 2M floats   (ffn mid)
  float* ZX   = R;             // 4.57M floats (in_proj -> gate)
  float* H    = ws + 7 * MG;   // 1M, persistent residual
  float* ATMP = ws + 8 * MG;   // 1M, ln outs / final pre-add
  float* XC   = ws + 9 * MG;   // 2.62M
  float* Y    = ws + 12 * MG;  // 2M
  float* out  = (float*)d_out;

  prep_k<<<513, 256, 0, stream>>>(w_in, b_in, c1w, bn1g, bn1b, c2w, bn2g, bn2b,
                                  wq, wk, wv, W1, W2, SC, BQKV);
  // fused (x@w_in -> conv1 -> bn -> gelu):  (32768x128)@(128x128)
  gemm_k<EPI_BNGELU, 64><<<dim3(512, 1), 256, 0, stream>>>(
      x, W1, OUT1, nullptr, SC, SC + 128, 32768, 128, 128);
  // conv2 -> bn -> gelu: (8192x512)@(512x128)
  gemm_k<EPI_BNGELU, 32><<<dim3(256, 1), 256, 0, stream>>>(
      OUT1, W2, H, nullptr, SC + 256, SC + 384, 8192, 128, 512);
  ln_rows_k<<<2048, 256, 0, stream>>>(H, ATMP, ln1g, ln1b);
  // fused q|k|v projection, elu+1 on q,k
  gemm_k<EPI_QKV, 32><<<dim3(256, 3), 256, 0, stream>>>(
      ATMP, BQKV, QKV, nullptr, nullptr, nullptr, 8192, 384, 128);
  attn_kv_k<<<64, 256, 0, stream>>>(QKV, KV, KS);
  attn_apply_k<<<8192, 128, 0, stream>>>(QKV, KV, KS, ATTN);
  // h += attn@wo + bo
  gemm_k<EPI_RESBIAS, 32><<<dim3(256, 1), 256, 0, stream>>>(
      ATTN, wo, H, H, bo, nullptr, 8192, 128, 128);
  ln_rows_k<<<2048, 256, 0, stream>>>(H, ATMP, ln2g, ln2b);
  gemm_k<EPI_BIASGELU, 32><<<dim3(256, 2), 256, 0, stream>>>(
      ATMP, ff1w, MID, nullptr, ff1b, nullptr, 8192, 256, 128);
  gemm_k<EPI_RESBIAS, 32><<<dim3(256, 1), 256, 0, stream>>>(
      MID, ff2w, H, H, ff2b, nullptr, 8192, 128, 256);
  // in_proj: (8192x128)@(128x584)
  gemm_k<EPI_NONE, 32><<<dim3(256, 5), 256, 0, stream>>>(
      H, ipw, ZX, nullptr, nullptr, nullptr, 8192, 584, 128);
  mamba_conv_k<<<8192, 320, 0, stream>>>(ZX, cw, cb, dtb, XC, DT);
  scan_k<<<128, 1024, 0, stream>>>(XC, DT, Alog, Dsk, Y);
  gate_rms_k<<<8192, 256, 0, stream>>>(Y, ZX, mnw);
  gemm_k<EPI_NONE, 32><<<dim3(256, 1), 256, 0, stream>>>(
      Y, outw, ATMP, nullptr, nullptr, nullptr, 8192, 128, 256);
  final_k<<<2048, 256, 0, stream>>>(ATMP, H, rmsw, olng, olnb, out);
  (void)in_sizes; (void)n_in; (void)out_size; (void)ws_size;
}

// Round 3
// 545.749 us; speedup vs baseline: 1.1846x; 1.1846x over previous
//
#include <hip/hip_runtime.h>
#include <cstdint>
#include <cstddef>

// Shapes
// B=16, L=16384, E=16, H=128, NH=4, DH=32, FF=256, D_STATE=32, HEADDIM=32
// D_INNER=256, NHEADS=8, CONV_DIM=320, DCONV=4, LC=512, ROWS=B*LC=8192

#define EPI_NONE 0
#define EPI_BNGELU 1
#define EPI_QKV 2
#define EPI_RESBIAS 3
#define EPI_BIASGELU 4

static __device__ __forceinline__ float gelu_f(float x) {
  float t = tanhf(0.7978845608028654f * (x + 0.044715f * x * x * x));
  return 0.5f * x * (1.0f + t);
}

// ---------------- prep: effective conv weights, BN folding, qkv pack ----------------
__global__ __launch_bounds__(256) void prep_k(
    const float* __restrict__ w_in, const float* __restrict__ b_in,
    const float* __restrict__ c1w, const float* __restrict__ bn1g,
    const float* __restrict__ bn1b, const float* __restrict__ c2w,
    const float* __restrict__ bn2g, const float* __restrict__ bn2b,
    const float* __restrict__ wq, const float* __restrict__ wk,
    const float* __restrict__ wv,
    float* __restrict__ W1, float* __restrict__ W2,
    float* __restrict__ sc, float* __restrict__ Bqkv) {
  int idx = blockIdx.x * 256 + threadIdx.x;
  const float inv = rsqrtf(1.0f + 1e-5f);
  if (idx < 16384) {
    // W1eff[k=(i*16+e)][c] = sum_cin w_in[e,cin]*conv1_w[c,cin,i]
    int k = idx >> 7, c = idx & 127;
    int e = k & 15, i = k >> 4;
    float s = 0.f;
    #pragma unroll 4
    for (int cin = 0; cin < 128; ++cin)
      s += w_in[e * 128 + cin] * c1w[c * 1024 + cin * 8 + i];
    W1[idx] = s;
  } else if (idx < 16384 + 65536) {
    // W2eff[k=(i*128+cin)][c] = conv2_w[c,cin,i]
    int j = idx - 16384;
    int k = j >> 7, c = j & 127;
    int i = k >> 7, cin = k & 127;
    W2[j] = c2w[c * 512 + cin * 4 + i];
  } else if (idx < 16384 + 65536 + 128) {
    int c = idx - (16384 + 65536);
    float b1 = 0.f;
    for (int cin = 0; cin < 128; ++cin) {
      float bi = b_in[cin];
      #pragma unroll
      for (int i = 0; i < 8; ++i) b1 += bi * c1w[c * 1024 + cin * 8 + i];
    }
    float s1 = bn1g[c] * inv;
    sc[c] = s1;                       // scale1
    sc[128 + c] = b1 * s1 + bn1b[c];  // shift1 (conv bias folded)
    sc[256 + c] = bn2g[c] * inv;      // scale2
    sc[384 + c] = bn2b[c];            // shift2
  } else {
    int j = idx - (16384 + 65536 + 128);
    if (j < 128 * 384) {
      int k = j / 384, n = j % 384;
      float v = (n < 128) ? wq[k * 128 + n]
              : (n < 256) ? wk[k * 128 + (n - 128)]
                          : wv[k * 128 + (n - 256)];
      Bqkv[j] = v;
    }
  }
}

// ---------------- generic fp32 GEMM, row-major, BM x 128 x BK=32, 256 thr ----------------
template <int EPI, int BM>
__global__ __launch_bounds__(256) void gemm_k(
    const float* __restrict__ A, const float* __restrict__ B,
    float* __restrict__ C, const float* __restrict__ Cres,
    const float* __restrict__ v0, const float* __restrict__ v1,
    int M, int N, int K) {
  constexpr int RT = BM / 8;
  __shared__ float As[BM][33];   // [m][k], pad 1
  __shared__ float Bs[32][128];  // [k][n]
  const int tid = threadIdx.x;
  const int row0 = blockIdx.x * BM;
  const int n0 = blockIdx.y * 128;
  const int tr = tid >> 5, tc = tid & 31;
  float acc[RT][4];
  #pragma unroll
  for (int i = 0; i < RT; ++i)
    for (int j = 0; j < 4; ++j) acc[i][j] = 0.f;

  for (int k0 = 0; k0 < K; k0 += 32) {
    #pragma unroll
    for (int i = 0; i < BM / 32; ++i) {
      int j = i * 256 + tid;
      int m = j >> 3, k4 = (j & 7) << 2;
      const float4 av = *(const float4*)(A + (size_t)(row0 + m) * K + k0 + k4);
      As[m][k4] = av.x; As[m][k4 + 1] = av.y; As[m][k4 + 2] = av.z; As[m][k4 + 3] = av.w;
    }
    #pragma unroll
    for (int i = 0; i < 4; ++i) {
      int j = i * 256 + tid;
      int kk = j >> 5, c4 = (j & 31) << 2;
      float4 bv = make_float4(0.f, 0.f, 0.f, 0.f);
      if (n0 + c4 < N) bv = *(const float4*)(B + (size_t)(k0 + kk) * N + n0 + c4);
      *(float4*)&Bs[kk][c4] = bv;
    }
    __syncthreads();
    #pragma unroll
    for (int kk = 0; kk < 32; ++kk) {
      const float4 bv = *(const float4*)&Bs[kk][tc << 2];
      #pragma unroll
      for (int i = 0; i < RT; ++i) {
        float a = As[tr * RT + i][kk];
        acc[i][0] = fmaf(a, bv.x, acc[i][0]);
        acc[i][1] = fmaf(a, bv.y, acc[i][1]);
        acc[i][2] = fmaf(a, bv.z, acc[i][2]);
        acc[i][3] = fmaf(a, bv.w, acc[i][3]);
      }
    }
    __syncthreads();
  }

  int cc = n0 + (tc << 2);
  if (cc >= N) return;
  #pragma unroll
  for (int i = 0; i < RT; ++i) {
    int rr = row0 + tr * RT + i;
    float o[4];
    #pragma unroll
    for (int jj = 0; jj < 4; ++jj) {
      float x = acc[i][jj];
      if (EPI == EPI_BNGELU) x = gelu_f(x * v0[cc + jj] + v1[cc + jj]);
      else if (EPI == EPI_QKV) { if (cc + jj < 256) x = (x > 0.f) ? x + 1.f : __expf(x); }
      else if (EPI == EPI_RESBIAS) x = Cres[(size_t)rr * N + cc + jj] + x + v0[cc + jj];
      else if (EPI == EPI_BIASGELU) x = gelu_f(x + v0[cc + jj]);
      o[jj] = x;
    }
    *(float4*)(C + (size_t)rr * N + cc) = make_float4(o[0], o[1], o[2], o[3]);
  }
}

// ---------------- LayerNorm over 128, one wave per row ----------------
__global__ __launch_bounds__(256) void ln_rows_k(
    const float* __restrict__ in, float* __restrict__ out,
    const float* __restrict__ g, const float* __restrict__ b) {
  int r = (blockIdx.x << 2) + (threadIdx.x >> 6);
  int lane = threadIdx.x & 63;
  size_t base = (size_t)r * 128 + lane * 2;
  float2 v = *(const float2*)(in + base);
  float s = v.x + v.y, q = v.x * v.x + v.y * v.y;
  #pragma unroll
  for (int off = 1; off < 64; off <<= 1) {
    s += __shfl_xor(s, off);
    q += __shfl_xor(q, off);
  }
  float m = s * (1.f / 128.f);
  float var = q * (1.f / 128.f) - m * m;
  float rs = rsqrtf(var + 1e-5f);
  float2 gg = *(const float2*)(g + lane * 2);
  float2 bb = *(const float2*)(b + lane * 2);
  float2 o;
  o.x = (v.x - m) * rs * gg.x + bb.x;
  o.y = (v.y - m) * rs * gg.y + bb.y;
  *(float2*)(out + base) = o;
}

// ---------------- linear-attn: kv[b,h,d,e] and ksum[b,h,d] ----------------
__global__ __launch_bounds__(256) void attn_kv_k(
    const float* __restrict__ qkv, float* __restrict__ kv, float* __restrict__ ksum) {
  int bh = blockIdx.x;  // b*4+h
  int b = bh >> 2, h = bh & 3;
  int t = threadIdx.x;
  int d = t >> 3, e4 = (t & 7) << 2;
  __shared__ float ks[8][32], vs[8][32];
  float a0 = 0, a1 = 0, a2 = 0, a3 = 0, ksa = 0;
  size_t base = (size_t)b * 512 * 384;
  for (int lc = 0; lc < 512; lc += 8) {
    #pragma unroll
    for (int i = 0; i < 2; ++i) {
      int j = i * 256 + t;
      int rl = j >> 6, rem = j & 63, half = rem >> 5, col = rem & 31;
      float val = qkv[base + (size_t)(lc + rl) * 384 + 128 + half * 128 + h * 32 + col];
      if (half) vs[rl][col] = val; else ks[rl][col] = val;
    }
    __syncthreads();
    #pragma unroll
    for (int r = 0; r < 8; ++r) {
      float kd = ks[r][d];
      if ((t & 7) == 0) ksa += kd;
      a0 = fmaf(kd, vs[r][e4 + 0], a0);
      a1 = fmaf(kd, vs[r][e4 + 1], a1);
      a2 = fmaf(kd, vs[r][e4 + 2], a2);
      a3 = fmaf(kd, vs[r][e4 + 3], a3);
    }
    __syncthreads();
  }
  float* kvp = kv + (size_t)bh * 1024 + d * 32 + e4;
  kvp[0] = a0; kvp[1] = a1; kvp[2] = a2; kvp[3] = a3;
  if ((t & 7) == 0) ksum[bh * 32 + d] = ksa;
}

// ---------------- linear-attn apply: attn = (q@kv) / (q.ksum + 1e-6) ----------------
__global__ __launch_bounds__(128) void attn_apply_k(
    const float* __restrict__ qkv, const float* __restrict__ kv,
    const float* __restrict__ ksum, float* __restrict__ attn) {
  int row = blockIdx.x;
  int t = threadIdx.x, h = t >> 5, e = t & 31;
  int b = row >> 9;
  const float* qr = qkv + (size_t)row * 384 + h * 32;
  const float* kvp = kv + (size_t)(b * 4 + h) * 1024;
  const float* ksp = ksum + (b * 4 + h) * 32;
  float num = 0.f, den = 0.f;
  #pragma unroll 8
  for (int d = 0; d < 32; ++d) {
    float qd = qr[d];
    num = fmaf(qd, kvp[d * 32 + e], num);
    den = fmaf(qd, ksp[d], den);
  }
  attn[(size_t)row * 128 + t] = num / (den + 1e-6f);
}

// -------- mamba depthwise causal conv + silu; dt softplus; dA = exp(dt*A) --------
__global__ __launch_bounds__(320) void mamba_conv_k(
    const float* __restrict__ zx, const float* __restrict__ cw,
    const float* __restrict__ cb, const float* __restrict__ dtb,
    const float* __restrict__ Alog,
    float* __restrict__ xc, float* __restrict__ dt, float* __restrict__ da) {
  int row = blockIdx.x;  // b*512 + l
  int c = threadIdx.x;   // 0..319
  int l = row & 511;
  float acc = cb[c];
  #pragma unroll
  for (int i = 0; i < 4; ++i) {
    int dl = i - 3;
    if (l + dl >= 0)
      acc += zx[(size_t)(row + dl) * 584 + 256 + c] * cw[c * 4 + i];
  }
  float s = acc / (1.f + __expf(-acc));  // silu
  xc[(size_t)row * 320 + c] = s;
  if (c < 8) {
    float r = zx[(size_t)row * 584 + 576 + c] + dtb[c];
    float dtv = fmaxf(r, 0.f) + log1pf(__expf(-fabsf(r)));  // softplus
    dt[(size_t)row * 8 + c] = dtv;
    float Ah = -__expf(Alog[c]);
    da[(size_t)row * 8 + c] = __expf(dtv * Ah);
  }
}

// ---------------- SSM scan v2: latency-optimized ----------------
// 128 blocks = b(16) x pg(8).  256 threads: lane = nh(8) | pi(4-per-group? see below)
// lane bits: nh = lane&7 (n-octet, 4 n each), pi = (lane>>3)&3, h = wave*2 + (lane>>5).
// Thread state: 4 registers h[n]. y-dot local (4 fma) + 3-step shfl reduce.
struct ScanSt { float4 Bq, Cq; float dtv, dav, xs; };

__global__ __launch_bounds__(256) void scan_k(
    const float* __restrict__ xc, const float* __restrict__ dt,
    const float* __restrict__ da, const float* __restrict__ Dsk,
    float* __restrict__ y) {
  int bx = blockIdx.x;
  int b = bx >> 3, pg = bx & 7;
  int t = threadIdx.x;
  int lane = t & 63, w = t >> 6;
  int nh = lane & 7;
  int pi = (lane >> 3) & 3;
  int h = w * 2 + (lane >> 5);
  int p = pg * 4 + pi;
  float Dh = Dsk[h];
  float h0 = 0.f, h1 = 0.f, h2 = 0.f, h3 = 0.f;
  const size_t row0 = (size_t)b * 512;
  const float* dtp = dt + row0 * 8 + h;
  const float* dap = da + row0 * 8 + h;
  const float* xp  = xc + row0 * 320 + h * 32 + p;
  const float* Bp  = xc + row0 * 320 + 256 + nh * 4;
  const float* Cp  = xc + row0 * 320 + 288 + nh * 4;
  float* yp = y + row0 * 256 + h * 32 + p;

  auto ld = [&](int l) {
    ScanSt S;
    int lc = (l < 512) ? l : 511;
    S.dtv = dtp[(size_t)lc * 8];
    S.dav = dap[(size_t)lc * 8];
    S.xs  = xp[(size_t)lc * 320];
    S.Bq  = *(const float4*)(Bp + (size_t)lc * 320);
    S.Cq  = *(const float4*)(Cp + (size_t)lc * 320);
    return S;
  };
  auto stepc = [&](const ScanSt& S, int l) {
    float ux = S.dtv * S.xs;
    h0 = fmaf(h0, S.dav, ux * S.Bq.x);
    float yv = S.Cq.x * h0;
    h1 = fmaf(h1, S.dav, ux * S.Bq.y);
    yv = fmaf(S.Cq.y, h1, yv);
    h2 = fmaf(h2, S.dav, ux * S.Bq.z);
    yv = fmaf(S.Cq.z, h2, yv);
    h3 = fmaf(h3, S.dav, ux * S.Bq.w);
    yv = fmaf(S.Cq.w, h3, yv);
    yv += __shfl_xor(yv, 1);
    yv += __shfl_xor(yv, 2);
    yv += __shfl_xor(yv, 4);
    if (nh == 0) yp[(size_t)l * 256] = yv + Dh * S.xs;
  };

  ScanSt SA = ld(0), SB = ld(1);
  for (int l = 0; l < 512; l += 2) {
    ScanSt SC = ld(l + 2);
    ScanSt SD = ld(l + 3);
    stepc(SA, l);
    stepc(SB, l + 1);
    SA = SC; SB = SD;
  }
}

// ---------------- y gating: y *= silu(zg); RMS(256) * mnorm_w ----------------
__global__ __launch_bounds__(256) void gate_rms_k(
    float* __restrict__ y, const float* __restrict__ zx, const float* __restrict__ mw) {
  int row = blockIdx.x;
  int c = threadIdx.x;
  float zg = zx[(size_t)row * 584 + c];
  float val = y[(size_t)row * 256 + c] * (zg / (1.f + __expf(-zg)));
  float sq = val * val;
  #pragma unroll
  for (int off = 1; off < 64; off <<= 1) sq += __shfl_xor(sq, off);
  __shared__ float ps[4];
  if ((c & 63) == 0) ps[c >> 6] = sq;
  __syncthreads();
  float tot = ps[0] + ps[1] + ps[2] + ps[3];
  y[(size_t)row * 256 + c] = val * rsqrtf(tot * (1.f / 256.f) + 1e-6f) * mw[c];
}

// ---------------- final: RMS(t + residual) then LN ----------------
__global__ __launch_bounds__(256) void final_k(
    const float* __restrict__ t, const float* __restrict__ hres,
    const float* __restrict__ rmsw, const float* __restrict__ g,
    const float* __restrict__ b, float* __restrict__ out) {
  int r = (blockIdx.x << 2) + (threadIdx.x >> 6);
  int lane = threadIdx.x & 63;
  size_t base = (size_t)r * 128 + lane * 2;
  float2 tv = *(const float2*)(t + base);
  float2 hv = *(const float2*)(hres + base);
  float vx = tv.x + hv.x, vy = tv.y + hv.y;
  float sq = vx * vx + vy * vy;
  #pragma unroll
  for (int off = 1; off < 64; off <<= 1) sq += __shfl_xor(sq, off);
  float rs = rsqrtf(sq * (1.f / 128.f) + 1e-6f);
  float rx = vx * rs * rmsw[lane * 2], ry = vy * rs * rmsw[lane * 2 + 1];
  float s = rx + ry, q2 = rx * rx + ry * ry;
  #pragma unroll
  for (int off = 1; off < 64; off <<= 1) {
    s += __shfl_xor(s, off);
    q2 += __shfl_xor(q2, off);
  }
  float m = s * (1.f / 128.f), var = q2 * (1.f / 128.f) - m * m;
  float inv = rsqrtf(var + 1e-5f);
  float2 o;
  o.x = (rx - m) * inv * g[lane * 2] + b[lane * 2];
  o.y = (ry - m) * inv * g[lane * 2 + 1] + b[lane * 2 + 1];
  *(float2*)(out + base) = o;
}

extern "C" void kernel_launch(void* const* d_in, const int* in_sizes, int n_in,
                              void* d_out, int out_size, void* d_ws, size_t ws_size,
                              hipStream_t stream) {
  const float* x      = (const float*)d_in[0];
  const float* w_in   = (const float*)d_in[1];
  const float* b_in   = (const float*)d_in[2];
  const float* c1w    = (const float*)d_in[3];
  const float* bn1g   = (const float*)d_in[4];
  const float* bn1b   = (const float*)d_in[5];
  const float* c2w    = (const float*)d_in[6];
  const float* bn2g   = (const float*)d_in[7];
  const float* bn2b   = (const float*)d_in[8];
  const float* ln1g   = (const float*)d_in[9];
  const float* ln1b   = (const float*)d_in[10];
  const float* wq     = (const float*)d_in[11];
  const float* wk     = (const float*)d_in[12];
  const float* wv     = (const float*)d_in[13];
  const float* wo     = (const float*)d_in[14];
  const float* bo     = (const float*)d_in[15];
  const float* ln2g   = (const float*)d_in[16];
  const float* ln2b   = (const float*)d_in[17];
  const float* ff1w   = (const float*)d_in[18];
  const float* ff1b   = (const float*)d_in[19];
  const float* ff2w   = (const float*)d_in[20];
  const float* ff2b   = (const float*)d_in[21];
  const float* ipw    = (const float*)d_in[22];
  const float* cw     = (const float*)d_in[23];
  const float* cb     = (const float*)d_in[24];
  const float* dtb    = (const float*)d_in[25];
  const float* Alog   = (const float*)d_in[26];
  const float* Dsk    = (const float*)d_in[27];
  const float* mnw    = (const float*)d_in[28];
  const float* outw   = (const float*)d_in[29];
  const float* rmsw   = (const float*)d_in[30];
  const float* olng   = (const float*)d_in[31];
  const float* olnb   = (const float*)d_in[32];

  float* ws = (float*)d_ws;
  const size_t MG = 1u << 20;
  // small region (< 1M floats)
  float* W1   = ws + 0;        // 16384
  float* W2   = ws + 16384;    // 65536
  float* SC   = ws + 81920;    // 512
  float* BQKV = ws + 82432;    // 49152
  float* KV   = ws + 131584;   // 65536
  float* KS   = ws + 197120;   // 2048
  float* DT   = ws + 199168;   // 65536
  float* DA   = ws + 264704;   // 65536
  // big region R at 1M..~7M, time-multiplexed
  float* R    = ws + MG;
  float* OUT1 = R;             // 4M floats   (gemm1 -> gemm2)
  float* QKV  = R;             // 3M floats   (qkv -> attn)
  float* ATTN = R + 3 * MG;    // 1M floats
  float* MID  = R;             // 2M floats   (ffn mid)
  float* ZX   = R;             // 4.57M floats (in_proj -> gate)
  float* H    = ws + 7 * MG;   // 1M, persistent residual
  float* ATMP = ws + 8 * MG;   // 1M, ln outs / final pre-add
  float* XC   = ws + 9 * MG;   // 2.62M
  float* Y    = ws + 12 * MG;  // 2M
  float* out  = (float*)d_out;

  prep_k<<<513, 256, 0, stream>>>(w_in, b_in, c1w, bn1g, bn1b, c2w, bn2g, bn2b,
                                  wq, wk, wv, W1, W2, SC, BQKV);
  // fused (x@w_in -> conv1 -> bn -> gelu):  (32768x128)@(128x128)
  gemm_k<EPI_BNGELU, 64><<<dim3(512, 1), 256, 0, stream>>>(
      x, W1, OUT1, nullptr, SC, SC + 128, 32768, 128, 128);
  // conv2 -> bn -> gelu: (8192x512)@(512x128)
  gemm_k<EPI_BNGELU, 32><<<dim3(256, 1), 256, 0, stream>>>(
      OUT1, W2, H, nullptr, SC + 256, SC + 384, 8192, 128, 512);
  ln_rows_k<<<2048, 256, 0, stream>>>(H, ATMP, ln1g, ln1b);
  // fused q|k|v projection, elu+1 on q,k
  gemm_k<EPI_QKV, 32><<<dim3(256, 3), 256, 0, stream>>>(
      ATMP, BQKV, QKV, nullptr, nullptr, nullptr, 8192, 384, 128);
  attn_kv_k<<<64, 256, 0, stream>>>(QKV, KV, KS);
  attn_apply_k<<<8192, 128, 0, stream>>>(QKV, KV, KS, ATTN);
  // h += attn@wo + bo
  gemm_k<EPI_RESBIAS, 32><<<dim3(256, 1), 256, 0, stream>>>(
      ATTN, wo, H, H, bo, nullptr, 8192, 128, 128);
  ln_rows_k<<<2048, 256, 0, stream>>>(H, ATMP, ln2g, ln2b);
  gemm_k<EPI_BIASGELU, 32><<<dim3(256, 2), 256, 0, stream>>>(
      ATMP, ff1w, MID, nullptr, ff1b, nullptr, 8192, 256, 128);
  gemm_k<EPI_RESBIAS, 32><<<dim3(256, 1), 256, 0, stream>>>(
      MID, ff2w, H, H, ff2b, nullptr, 8192, 128, 256);
  // in_proj: (8192x128)@(128x584)
  gemm_k<EPI_NONE, 32><<<dim3(256, 5), 256, 0, stream>>>(
      H, ipw, ZX, nullptr, nullptr, nullptr, 8192, 584, 128);
  mamba_conv_k<<<8192, 320, 0, stream>>>(ZX, cw, cb, dtb, Alog, XC, DT, DA);
  scan_k<<<128, 256, 0, stream>>>(XC, DT, DA, Dsk, Y);
  gate_rms_k<<<8192, 256, 0, stream>>>(Y, ZX, mnw);
  gemm_k<EPI_NONE, 32><<<dim3(256, 1), 256, 0, stream>>>(
      Y, outw, ATMP, nullptr, nullptr, nullptr, 8192, 128, 256);
  final_k<<<2048, 256, 0, stream>>>(ATMP, H, rmsw, olng, olnb, out);
  (void)in_sizes; (void)n_in; (void)out_size; (void)ws_size;
}

// Round 9
// 455.515 us; speedup vs baseline: 1.4193x; 1.1981x over previous
//
#include <hip/hip_runtime.h>
#include <cstdint>
#include <cstddef>

// Shapes
// B=16, L=16384, E=16, H=128, NH=4, DH=32, FF=256, D_STATE=32, HEADDIM=32
// D_INNER=256, NHEADS=8, CONV_DIM=320, DCONV=4, LC=512, ROWS=B*LC=8192

#define EPI_NONE 0
#define EPI_BNGELU 1
#define EPI_QKV 2
#define EPI_RESBIAS 3
#define EPI_BIASGELU 4

static __device__ __forceinline__ float gelu_f(float x) {
  float t = tanhf(0.7978845608028654f * (x + 0.044715f * x * x * x));
  return 0.5f * x * (1.0f + t);
}

// ---------------- prep: effective conv weights, BN folding, qkv pack ----------------
__global__ __launch_bounds__(256) void prep_k(
    const float* __restrict__ w_in, const float* __restrict__ b_in,
    const float* __restrict__ c1w, const float* __restrict__ bn1g,
    const float* __restrict__ bn1b, const float* __restrict__ c2w,
    const float* __restrict__ bn2g, const float* __restrict__ bn2b,
    const float* __restrict__ wq, const float* __restrict__ wk,
    const float* __restrict__ wv,
    float* __restrict__ W1, float* __restrict__ W2,
    float* __restrict__ sc, float* __restrict__ Bqkv) {
  int idx = blockIdx.x * 256 + threadIdx.x;
  const float inv = rsqrtf(1.0f + 1e-5f);
  if (idx < 16384) {
    int k = idx >> 7, c = idx & 127;
    int e = k & 15, i = k >> 4;
    float s = 0.f;
    #pragma unroll 4
    for (int cin = 0; cin < 128; ++cin)
      s += w_in[e * 128 + cin] * c1w[c * 1024 + cin * 8 + i];
    W1[idx] = s;
  } else if (idx < 16384 + 65536) {
    int j = idx - 16384;
    int k = j >> 7, c = j & 127;
    int i = k >> 7, cin = k & 127;
    W2[j] = c2w[c * 512 + cin * 4 + i];
  } else if (idx < 16384 + 65536 + 128) {
    int c = idx - (16384 + 65536);
    float b1 = 0.f;
    for (int cin = 0; cin < 128; ++cin) {
      float bi = b_in[cin];
      #pragma unroll
      for (int i = 0; i < 8; ++i) b1 += bi * c1w[c * 1024 + cin * 8 + i];
    }
    float s1 = bn1g[c] * inv;
    sc[c] = s1;
    sc[128 + c] = b1 * s1 + bn1b[c];
    sc[256 + c] = bn2g[c] * inv;
    sc[384 + c] = bn2b[c];
  } else {
    int j = idx - (16384 + 65536 + 128);
    if (j < 128 * 384) {
      int k = j / 384, n = j % 384;
      float v = (n < 128) ? wq[k * 128 + n]
              : (n < 256) ? wk[k * 128 + (n - 128)]
                          : wv[k * 128 + (n - 256)];
      Bqkv[j] = v;
    }
  }
}

// ---------------- generic fp32 GEMM, row-major, BM x 128 x BK=32, 256 thr ----------------
template <int EPI, int BM>
__global__ __launch_bounds__(256) void gemm_k(
    const float* __restrict__ A, const float* __restrict__ B,
    float* __restrict__ C, const float* __restrict__ Cres,
    const float* __restrict__ v0, const float* __restrict__ v1,
    int M, int N, int K) {
  constexpr int RT = BM / 8;
  __shared__ float As[BM][33];
  __shared__ float Bs[32][128];
  const int tid = threadIdx.x;
  const int row0 = blockIdx.x * BM;
  const int n0 = blockIdx.y * 128;
  const int tr = tid >> 5, tc = tid & 31;
  float acc[RT][4];
  #pragma unroll
  for (int i = 0; i < RT; ++i)
    for (int j = 0; j < 4; ++j) acc[i][j] = 0.f;

  for (int k0 = 0; k0 < K; k0 += 32) {
    #pragma unroll
    for (int i = 0; i < BM / 32; ++i) {
      int j = i * 256 + tid;
      int m = j >> 3, k4 = (j & 7) << 2;
      const float4 av = *(const float4*)(A + (size_t)(row0 + m) * K + k0 + k4);
      As[m][k4] = av.x; As[m][k4 + 1] = av.y; As[m][k4 + 2] = av.z; As[m][k4 + 3] = av.w;
    }
    #pragma unroll
    for (int i = 0; i < 4; ++i) {
      int j = i * 256 + tid;
      int kk = j >> 5, c4 = (j & 31) << 2;
      float4 bv = make_float4(0.f, 0.f, 0.f, 0.f);
      if (n0 + c4 < N) bv = *(const float4*)(B + (size_t)(k0 + kk) * N + n0 + c4);
      *(float4*)&Bs[kk][c4] = bv;
    }
    __syncthreads();
    #pragma unroll
    for (int kk = 0; kk < 32; ++kk) {
      const float4 bv = *(const float4*)&Bs[kk][tc << 2];
      #pragma unroll
      for (int i = 0; i < RT; ++i) {
        float a = As[tr * RT + i][kk];
        acc[i][0] = fmaf(a, bv.x, acc[i][0]);
        acc[i][1] = fmaf(a, bv.y, acc[i][1]);
        acc[i][2] = fmaf(a, bv.z, acc[i][2]);
        acc[i][3] = fmaf(a, bv.w, acc[i][3]);
      }
    }
    __syncthreads();
  }

  int cc = n0 + (tc << 2);
  if (cc >= N) return;
  #pragma unroll
  for (int i = 0; i < RT; ++i) {
    int rr = row0 + tr * RT + i;
    float o[4];
    #pragma unroll
    for (int jj = 0; jj < 4; ++jj) {
      float x = acc[i][jj];
      if (EPI == EPI_BNGELU) x = gelu_f(x * v0[cc + jj] + v1[cc + jj]);
      else if (EPI == EPI_QKV) { if (cc + jj < 256) x = (x > 0.f) ? x + 1.f : __expf(x); }
      else if (EPI == EPI_RESBIAS) x = Cres[(size_t)rr * N + cc + jj] + x + v0[cc + jj];
      else if (EPI == EPI_BIASGELU) x = gelu_f(x + v0[cc + jj]);
      o[jj] = x;
    }
    *(float4*)(C + (size_t)rr * N + cc) = make_float4(o[0], o[1], o[2], o[3]);
  }
}

// ---------------- LayerNorm over 128, one wave per row ----------------
__global__ __launch_bounds__(256) void ln_rows_k(
    const float* __restrict__ in, float* __restrict__ out,
    const float* __restrict__ g, const float* __restrict__ b) {
  int r = (blockIdx.x << 2) + (threadIdx.x >> 6);
  int lane = threadIdx.x & 63;
  size_t base = (size_t)r * 128 + lane * 2;
  float2 v = *(const float2*)(in + base);
  float s = v.x + v.y, q = v.x * v.x + v.y * v.y;
  #pragma unroll
  for (int off = 1; off < 64; off <<= 1) {
    s += __shfl_xor(s, off);
    q += __shfl_xor(q, off);
  }
  float m = s * (1.f / 128.f);
  float var = q * (1.f / 128.f) - m * m;
  float rs = rsqrtf(var + 1e-5f);
  float2 gg = *(const float2*)(g + lane * 2);
  float2 bb = *(const float2*)(b + lane * 2);
  float2 o;
  o.x = (v.x - m) * rs * gg.x + bb.x;
  o.y = (v.y - m) * rs * gg.y + bb.y;
  *(float2*)(out + base) = o;
}

// ---------------- linear-attn: kv[b,h,d,e] and ksum[b,h,d] ----------------
__global__ __launch_bounds__(256) void attn_kv_k(
    const float* __restrict__ qkv, float* __restrict__ kv, float* __restrict__ ksum) {
  int bh = blockIdx.x;  // b*4+h
  int b = bh >> 2, h = bh & 3;
  int t = threadIdx.x;
  int d = t >> 3, e4 = (t & 7) << 2;
  __shared__ float ks[8][32], vs[8][32];
  float a0 = 0, a1 = 0, a2 = 0, a3 = 0, ksa = 0;
  size_t base = (size_t)b * 512 * 384;
  for (int lc = 0; lc < 512; lc += 8) {
    #pragma unroll
    for (int i = 0; i < 2; ++i) {
      int j = i * 256 + t;
      int rl = j >> 6, rem = j & 63, half = rem >> 5, col = rem & 31;
      float val = qkv[base + (size_t)(lc + rl) * 384 + 128 + half * 128 + h * 32 + col];
      if (half) vs[rl][col] = val; else ks[rl][col] = val;
    }
    __syncthreads();
    #pragma unroll
    for (int r = 0; r < 8; ++r) {
      float kd = ks[r][d];
      if ((t & 7) == 0) ksa += kd;
      a0 = fmaf(kd, vs[r][e4 + 0], a0);
      a1 = fmaf(kd, vs[r][e4 + 1], a1);
      a2 = fmaf(kd, vs[r][e4 + 2], a2);
      a3 = fmaf(kd, vs[r][e4 + 3], a3);
    }
    __syncthreads();
  }
  float* kvp = kv + (size_t)bh * 1024 + d * 32 + e4;
  kvp[0] = a0; kvp[1] = a1; kvp[2] = a2; kvp[3] = a3;
  if ((t & 7) == 0) ksum[bh * 32 + d] = ksa;
}

// ---------------- linear-attn apply ----------------
__global__ __launch_bounds__(128) void attn_apply_k(
    const float* __restrict__ qkv, const float* __restrict__ kv,
    const float* __restrict__ ksum, float* __restrict__ attn) {
  int row = blockIdx.x;
  int t = threadIdx.x, h = t >> 5, e = t & 31;
  int b = row >> 9;
  const float* qr = qkv + (size_t)row * 384 + h * 32;
  const float* kvp = kv + (size_t)(b * 4 + h) * 1024;
  const float* ksp = ksum + (b * 4 + h) * 32;
  float num = 0.f, den = 0.f;
  #pragma unroll 8
  for (int d = 0; d < 32; ++d) {
    float qd = qr[d];
    num = fmaf(qd, kvp[d * 32 + e], num);
    den = fmaf(qd, ksp[d], den);
  }
  attn[(size_t)row * 128 + t] = num / (den + 1e-6f);
}

// -------- mamba depthwise causal conv + silu; dt softplus; dA = exp(dt*A) --------
__global__ __launch_bounds__(320) void mamba_conv_k(
    const float* __restrict__ zx, const float* __restrict__ cw,
    const float* __restrict__ cb, const float* __restrict__ dtb,
    const float* __restrict__ Alog,
    float* __restrict__ xc, float* __restrict__ dt, float* __restrict__ da) {
  int row = blockIdx.x;  // b*512 + l
  int c = threadIdx.x;   // 0..319
  int l = row & 511;
  float acc = cb[c];
  #pragma unroll
  for (int i = 0; i < 4; ++i) {
    int dl = i - 3;
    if (l + dl >= 0)
      acc += zx[(size_t)(row + dl) * 584 + 256 + c] * cw[c * 4 + i];
  }
  float s = acc / (1.f + __expf(-acc));  // silu
  xc[(size_t)row * 320 + c] = s;
  if (c < 8) {
    float r = zx[(size_t)row * 584 + 576 + c] + dtb[c];
    float dtv = fmaxf(r, 0.f) + log1pf(__expf(-fabsf(r)));  // softplus
    dt[(size_t)row * 8 + c] = dtv;
    float Ah = -__expf(Alog[c]);
    da[(size_t)row * 8 + c] = __expf(dtv * Ah);
  }
}

// ---------------- SSM scan v3: chunked parallel scan ----------------
// Phase A: local scan per (b,h,chunk of 32). 2048 blocks x 256 thr -> full TLP.
// Thread (p = t>>3, nh = t&7) owns 4 n. Writes y_local(+D skip), cumda, E_c, A_c.
__global__ __launch_bounds__(256) void scan_chunk_k(
    const float* __restrict__ xc, const float* __restrict__ dt,
    const float* __restrict__ da, const float* __restrict__ Dsk,
    float* __restrict__ y, float* __restrict__ ech,
    float* __restrict__ ach, float* __restrict__ cum) {
  int bx = blockIdx.x;  // h*256 + b*16 + c  (8 h-blocks of same (b,c) share an XCD)
  int h = bx >> 8, b = (bx >> 4) & 15, c = bx & 15;
  int t = threadIdx.x;
  int nh = t & 7, p = t >> 3;
  float Dh = Dsk[h];
  float h0 = 0.f, h1 = 0.f, h2 = 0.f, h3 = 0.f, cp = 1.f;
  size_t row = (size_t)b * 512 + c * 32;
  const float* dtp = dt + row * 8 + h;
  const float* dap = da + row * 8 + h;
  const float* xp = xc + row * 320 + h * 32 + p;
  const float* Bp = xc + row * 320 + 256 + nh * 4;
  const float* Cp = xc + row * 320 + 288 + nh * 4;
  float* yp = y + row * 256 + h * 32 + p;
  int bh = b * 8 + h;
  float* cpo = cum + (size_t)bh * 512 + c * 32;
  #pragma unroll 4
  for (int l = 0; l < 32; ++l) {
    float dtv = dtp[l * 8];
    float dav = dap[l * 8];
    float xs = xp[(size_t)l * 320];
    float4 Bq = *(const float4*)(Bp + (size_t)l * 320);
    float4 Cq = *(const float4*)(Cp + (size_t)l * 320);
    float ux = dtv * xs;
    h0 = fmaf(h0, dav, ux * Bq.x);
    h1 = fmaf(h1, dav, ux * Bq.y);
    h2 = fmaf(h2, dav, ux * Bq.z);
    h3 = fmaf(h3, dav, ux * Bq.w);
    float yv = Cq.x * h0;
    yv = fmaf(Cq.y, h1, yv);
    yv = fmaf(Cq.z, h2, yv);
    yv = fmaf(Cq.w, h3, yv);
    yv += __shfl_xor(yv, 1);
    yv += __shfl_xor(yv, 2);
    yv += __shfl_xor(yv, 4);
    cp *= dav;
    if (nh == 0) yp[(size_t)l * 256] = yv + Dh * xs;
    if (t == 0) cpo[l] = cp;
  }
  *(float4*)(ech + ((size_t)(bh * 16 + c)) * 1024 + p * 32 + nh * 4) =
      make_float4(h0, h1, h2, h3);
  if (t == 0) ach[bh * 16 + c] = cp;
}

// Phase BC: serial chunk-combine (16 steps) + correction y[l] += cumda[l]*(C[l].H_in).
// 128 blocks (b*8+h) x 1024 thr. State role: (pq=t>>5, nq=t&31); corr role: (lw=t>>5, pp=t&31).
__global__ __launch_bounds__(1024) void scan_fix_k(
    const float* __restrict__ xc, const float* __restrict__ cum,
    const float* __restrict__ ech, const float* __restrict__ ach,
    float* __restrict__ y) {
  int bh = blockIdx.x;
  int b = bh >> 3, h = bh & 7;
  int t = threadIdx.x;
  int pq = t >> 5, nq = t & 31;
  int lw = t >> 5, pp = t & 31;
  __shared__ float Hs[32][33];
  float Hreg = 0.f;
  const size_t row0 = (size_t)b * 512;
  for (int c = 0; c < 16; ++c) {
    Hs[pq][nq] = Hreg;
    __syncthreads();
    // advance state for next chunk: H <- A_c*H + E_c
    float e = ech[((size_t)(bh * 16 + c)) * 1024 + t];
    float a = ach[bh * 16 + c];
    Hreg = fmaf(Hreg, a, e);
    if (c) {  // chunk 0 has H_in = 0: no correction
      int l = c * 32 + lw;
      size_t row = row0 + l;
      const float* Cr = xc + row * 320 + 288;
      float dot = 0.f;
      #pragma unroll 8
      for (int n = 0; n < 32; ++n) dot = fmaf(Cr[n], Hs[pp][n], dot);
      float cd = cum[(size_t)bh * 512 + l];
      y[row * 256 + h * 32 + pp] += cd * dot;
    }
    __syncthreads();
  }
}

// ---------------- y gating: y *= silu(zg); RMS(256) * mnorm_w ----------------
__global__ __launch_bounds__(256) void gate_rms_k(
    float* __restrict__ y, const float* __restrict__ zx, const float* __restrict__ mw) {
  int row = blockIdx.x;
  int c = threadIdx.x;
  float zg = zx[(size_t)row * 584 + c];
  float val = y[(size_t)row * 256 + c] * (zg / (1.f + __expf(-zg)));
  float sq = val * val;
  #pragma unroll
  for (int off = 1; off < 64; off <<= 1) sq += __shfl_xor(sq, off);
  __shared__ float ps[4];
  if ((c & 63) == 0) ps[c >> 6] = sq;
  __syncthreads();
  float tot = ps[0] + ps[1] + ps[2] + ps[3];
  y[(size_t)row * 256 + c] = val * rsqrtf(tot * (1.f / 256.f) + 1e-6f) * mw[c];
}

// ---------------- final: RMS(t + residual) then LN ----------------
__global__ __launch_bounds__(256) void final_k(
    const float* __restrict__ t, const float* __restrict__ hres,
    const float* __restrict__ rmsw, const float* __restrict__ g,
    const float* __restrict__ b, float* __restrict__ out) {
  int r = (blockIdx.x << 2) + (threadIdx.x >> 6);
  int lane = threadIdx.x & 63;
  size_t base = (size_t)r * 128 + lane * 2;
  float2 tv = *(const float2*)(t + base);
  float2 hv = *(const float2*)(hres + base);
  float vx = tv.x + hv.x, vy = tv.y + hv.y;
  float sq = vx * vx + vy * vy;
  #pragma unroll
  for (int off = 1; off < 64; off <<= 1) sq += __shfl_xor(sq, off);
  float rs = rsqrtf(sq * (1.f / 128.f) + 1e-6f);
  float rx = vx * rs * rmsw[lane * 2], ry = vy * rs * rmsw[lane * 2 + 1];
  float s = rx + ry, q2 = rx * rx + ry * ry;
  #pragma unroll
  for (int off = 1; off < 64; off <<= 1) {
    s += __shfl_xor(s, off);
    q2 += __shfl_xor(q2, off);
  }
  float m = s * (1.f / 128.f), var = q2 * (1.f / 128.f) - m * m;
  float inv = rsqrtf(var + 1e-5f);
  float2 o;
  o.x = (rx - m) * inv * g[lane * 2] + b[lane * 2];
  o.y = (ry - m) * inv * g[lane * 2 + 1] + b[lane * 2 + 1];
  *(float2*)(out + base) = o;
}

extern "C" void kernel_launch(void* const* d_in, const int* in_sizes, int n_in,
                              void* d_out, int out_size, void* d_ws, size_t ws_size,
                              hipStream_t stream) {
  const float* x      = (const float*)d_in[0];
  const float* w_in   = (const float*)d_in[1];
  const float* b_in   = (const float*)d_in[2];
  const float* c1w    = (const float*)d_in[3];
  const float* bn1g   = (const float*)d_in[4];
  const float* bn1b   = (const float*)d_in[5];
  const float* c2w    = (const float*)d_in[6];
  const float* bn2g   = (const float*)d_in[7];
  const float* bn2b   = (const float*)d_in[8];
  const float* ln1g   = (const float*)d_in[9];
  const float* ln1b   = (const float*)d_in[10];
  const float* wq     = (const float*)d_in[11];
  const float* wk     = (const float*)d_in[12];
  const float* wv     = (const float*)d_in[13];
  const float* wo     = (const float*)d_in[14];
  const float* bo     = (const float*)d_in[15];
  const float* ln2g   = (const float*)d_in[16];
  const float* ln2b   = (const float*)d_in[17];
  const float* ff1w   = (const float*)d_in[18];
  const float* ff1b   = (const float*)d_in[19];
  const float* ff2w   = (const float*)d_in[20];
  const float* ff2b   = (const float*)d_in[21];
  const float* ipw    = (const float*)d_in[22];
  const float* cw     = (const float*)d_in[23];
  const float* cb     = (const float*)d_in[24];
  const float* dtb    = (const float*)d_in[25];
  const float* Alog   = (const float*)d_in[26];
  const float* Dsk    = (const float*)d_in[27];
  const float* mnw    = (const float*)d_in[28];
  const float* outw   = (const float*)d_in[29];
  const float* rmsw   = (const float*)d_in[30];
  const float* olng   = (const float*)d_in[31];
  const float* olnb   = (const float*)d_in[32];

  float* ws = (float*)d_ws;
  const size_t MG = 1u << 20;
  // small region (< 1M floats)
  float* W1   = ws + 0;        // 16384
  float* W2   = ws + 16384;    // 65536
  float* SC   = ws + 81920;    // 512
  float* BQKV = ws + 82432;    // 49152
  float* KV   = ws + 131584;   // 65536
  float* KS   = ws + 197120;   // 2048
  float* DT   = ws + 199168;   // 65536
  float* DA   = ws + 264704;   // 65536
  float* CUM  = ws + 330240;   // 65536
  float* ACH  = ws + 395776;   // 2048
  // big region R at 1M..~5.57M, time-multiplexed
  float* R    = ws + MG;
  float* OUT1 = R;                       // 4M  (gemm1 -> gemm2)
  float* QKV  = R;                       // 3M  (qkv -> attn)
  float* ATTN = R + 3 * MG;              // 1M
  float* MID  = R;                       // 2M  (ffn mid)
  float* ZX   = R;                       // 4.57M (in_proj -> gate)
  float* ECH  = ws + 5 * MG + 786432;    // 2M at 5.75M..7.75M (scan chunk states)
  float* H    = ws + 8 * MG;             // 1M, persistent residual
  float* ATMP = ws + 9 * MG;             // 1M, ln outs / final pre-add
  float* XC   = ws + 10 * MG;            // 2.56M
  float* Y    = ws + 12 * MG + 786432;   // 2M at 12.75M..14.75M
  float* out  = (float*)d_out;

  prep_k<<<513, 256, 0, stream>>>(w_in, b_in, c1w, bn1g, bn1b, c2w, bn2g, bn2b,
                                  wq, wk, wv, W1, W2, SC, BQKV);
  // fused (x@w_in -> conv1 -> bn -> gelu):  (32768x128)@(128x128)
  gemm_k<EPI_BNGELU, 64><<<dim3(512, 1), 256, 0, stream>>>(
      x, W1, OUT1, nullptr, SC, SC + 128, 32768, 128, 128);
  // conv2 -> bn -> gelu: (8192x512)@(512x128)
  gemm_k<EPI_BNGELU, 32><<<dim3(256, 1), 256, 0, stream>>>(
      OUT1, W2, H, nullptr, SC + 256, SC + 384, 8192, 128, 512);
  ln_rows_k<<<2048, 256, 0, stream>>>(H, ATMP, ln1g, ln1b);
  // fused q|k|v projection, elu+1 on q,k
  gemm_k<EPI_QKV, 32><<<dim3(256, 3), 256, 0, stream>>>(
      ATMP, BQKV, QKV, nullptr, nullptr, nullptr, 8192, 384, 128);
  attn_kv_k<<<64, 256, 0, stream>>>(QKV, KV, KS);
  attn_apply_k<<<8192, 128, 0, stream>>>(QKV, KV, KS, ATTN);
  // h += attn@wo + bo
  gemm_k<EPI_RESBIAS, 32><<<dim3(256, 1), 256, 0, stream>>>(
      ATTN, wo, H, H, bo, nullptr, 8192, 128, 128);
  ln_rows_k<<<2048, 256, 0, stream>>>(H, ATMP, ln2g, ln2b);
  gemm_k<EPI_BIASGELU, 32><<<dim3(256, 2), 256, 0, stream>>>(
      ATMP, ff1w, MID, nullptr, ff1b, nullptr, 8192, 256, 128);
  gemm_k<EPI_RESBIAS, 32><<<dim3(256, 1), 256, 0, stream>>>(
      MID, ff2w, H, H, ff2b, nullptr, 8192, 128, 256);
  // in_proj: (8192x128)@(128x584)
  gemm_k<EPI_NONE, 32><<<dim3(256, 5), 256, 0, stream>>>(
      H, ipw, ZX, nullptr, nullptr, nullptr, 8192, 584, 128);
  mamba_conv_k<<<8192, 320, 0, stream>>>(ZX, cw, cb, dtb, Alog, XC, DT, DA);
  scan_chunk_k<<<2048, 256, 0, stream>>>(XC, DT, DA, Dsk, Y, ECH, ACH, CUM);
  scan_fix_k<<<128, 1024, 0, stream>>>(XC, CUM, ECH, ACH, Y);
  gate_rms_k<<<8192, 256, 0, stream>>>(Y, ZX, mnw);
  gemm_k<EPI_NONE, 32><<<dim3(256, 1), 256, 0, stream>>>(
      Y, outw, ATMP, nullptr, nullptr, nullptr, 8192, 128, 256);
  final_k<<<2048, 256, 0, stream>>>(ATMP, H, rmsw, olng, olnb, out);
  (void)in_sizes; (void)n_in; (void)out_size; (void)ws_size;
}

// Round 10
// 423.474 us; speedup vs baseline: 1.5267x; 1.0757x over previous
//
#include <hip/hip_runtime.h>
#include <cstdint>
#include <cstddef>

// Shapes
// B=16, L=16384, E=16, H=128, NH=4, DH=32, FF=256, D_STATE=32, HEADDIM=32
// D_INNER=256, NHEADS=8, CONV_DIM=320, DCONV=4, LC=512, ROWS=B*LC=8192

#define EPI_NONE 0
#define EPI_BNGELU 1
#define EPI_QKV 2
#define EPI_RESBIAS 3
#define EPI_BIASGELU 4

static __device__ __forceinline__ float gelu_f(float x) {
  float t = tanhf(0.7978845608028654f * (x + 0.044715f * x * x * x));
  return 0.5f * x * (1.0f + t);
}

// ---------------- prep: effective conv weights, BN folding, qkv pack ----------------
__global__ __launch_bounds__(256) void prep_k(
    const float* __restrict__ w_in, const float* __restrict__ b_in,
    const float* __restrict__ c1w, const float* __restrict__ bn1g,
    const float* __restrict__ bn1b, const float* __restrict__ c2w,
    const float* __restrict__ bn2g, const float* __restrict__ bn2b,
    const float* __restrict__ wq, const float* __restrict__ wk,
    const float* __restrict__ wv,
    float* __restrict__ W1, float* __restrict__ W2,
    float* __restrict__ sc, float* __restrict__ Bqkv) {
  int idx = blockIdx.x * 256 + threadIdx.x;
  const float inv = rsqrtf(1.0f + 1e-5f);
  if (idx < 16384) {
    int k = idx >> 7, c = idx & 127;
    int e = k & 15, i = k >> 4;
    float s = 0.f;
    #pragma unroll 4
    for (int cin = 0; cin < 128; ++cin)
      s += w_in[e * 128 + cin] * c1w[c * 1024 + cin * 8 + i];
    W1[idx] = s;
  } else if (idx < 16384 + 65536) {
    int j = idx - 16384;
    int k = j >> 7, c = j & 127;
    int i = k >> 7, cin = k & 127;
    W2[j] = c2w[c * 512 + cin * 4 + i];
  } else if (idx < 16384 + 65536 + 128) {
    int c = idx - (16384 + 65536);
    float b1 = 0.f;
    for (int cin = 0; cin < 128; ++cin) {
      float bi = b_in[cin];
      #pragma unroll
      for (int i = 0; i < 8; ++i) b1 += bi * c1w[c * 1024 + cin * 8 + i];
    }
    float s1 = bn1g[c] * inv;
    sc[c] = s1;
    sc[128 + c] = b1 * s1 + bn1b[c];
    sc[256 + c] = bn2g[c] * inv;
    sc[384 + c] = bn2b[c];
  } else {
    int j = idx - (16384 + 65536 + 128);
    if (j < 128 * 384) {
      int k = j / 384, n = j % 384;
      float v = (n < 128) ? wq[k * 128 + n]
              : (n < 256) ? wk[k * 128 + (n - 128)]
                          : wv[k * 128 + (n - 256)];
      Bqkv[j] = v;
    }
  }
}

// ---------------- generic fp32 GEMM, row-major, BM x 128 x BK=32, 256 thr ----------------
template <int EPI, int BM>
__global__ __launch_bounds__(256) void gemm_k(
    const float* __restrict__ A, const float* __restrict__ B,
    float* __restrict__ C, const float* __restrict__ Cres,
    const float* __restrict__ v0, const float* __restrict__ v1,
    int M, int N, int K) {
  constexpr int RT = BM / 8;
  __shared__ float As[BM][33];
  __shared__ float Bs[32][128];
  const int tid = threadIdx.x;
  const int row0 = blockIdx.x * BM;
  const int n0 = blockIdx.y * 128;
  const int tr = tid >> 5, tc = tid & 31;
  float acc[RT][4];
  #pragma unroll
  for (int i = 0; i < RT; ++i)
    for (int j = 0; j < 4; ++j) acc[i][j] = 0.f;

  for (int k0 = 0; k0 < K; k0 += 32) {
    #pragma unroll
    for (int i = 0; i < BM / 32; ++i) {
      int j = i * 256 + tid;
      int m = j >> 3, k4 = (j & 7) << 2;
      const float4 av = *(const float4*)(A + (size_t)(row0 + m) * K + k0 + k4);
      As[m][k4] = av.x; As[m][k4 + 1] = av.y; As[m][k4 + 2] = av.z; As[m][k4 + 3] = av.w;
    }
    #pragma unroll
    for (int i = 0; i < 4; ++i) {
      int j = i * 256 + tid;
      int kk = j >> 5, c4 = (j & 31) << 2;
      float4 bv = make_float4(0.f, 0.f, 0.f, 0.f);
      if (n0 + c4 < N) bv = *(const float4*)(B + (size_t)(k0 + kk) * N + n0 + c4);
      *(float4*)&Bs[kk][c4] = bv;
    }
    __syncthreads();
    #pragma unroll
    for (int kk = 0; kk < 32; ++kk) {
      const float4 bv = *(const float4*)&Bs[kk][tc << 2];
      #pragma unroll
      for (int i = 0; i < RT; ++i) {
        float a = As[tr * RT + i][kk];
        acc[i][0] = fmaf(a, bv.x, acc[i][0]);
        acc[i][1] = fmaf(a, bv.y, acc[i][1]);
        acc[i][2] = fmaf(a, bv.z, acc[i][2]);
        acc[i][3] = fmaf(a, bv.w, acc[i][3]);
      }
    }
    __syncthreads();
  }

  int cc = n0 + (tc << 2);
  if (cc >= N) return;
  #pragma unroll
  for (int i = 0; i < RT; ++i) {
    int rr = row0 + tr * RT + i;
    float o[4];
    #pragma unroll
    for (int jj = 0; jj < 4; ++jj) {
      float x = acc[i][jj];
      if (EPI == EPI_BNGELU) x = gelu_f(x * v0[cc + jj] + v1[cc + jj]);
      else if (EPI == EPI_QKV) { if (cc + jj < 256) x = (x > 0.f) ? x + 1.f : __expf(x); }
      else if (EPI == EPI_RESBIAS) x = Cres[(size_t)rr * N + cc + jj] + x + v0[cc + jj];
      else if (EPI == EPI_BIASGELU) x = gelu_f(x + v0[cc + jj]);
      o[jj] = x;
    }
    *(float4*)(C + (size_t)rr * N + cc) = make_float4(o[0], o[1], o[2], o[3]);
  }
}

// ---------------- LayerNorm over 128, one wave per row ----------------
__global__ __launch_bounds__(256) void ln_rows_k(
    const float* __restrict__ in, float* __restrict__ out,
    const float* __restrict__ g, const float* __restrict__ b) {
  int r = (blockIdx.x << 2) + (threadIdx.x >> 6);
  int lane = threadIdx.x & 63;
  size_t base = (size_t)r * 128 + lane * 2;
  float2 v = *(const float2*)(in + base);
  float s = v.x + v.y, q = v.x * v.x + v.y * v.y;
  #pragma unroll
  for (int off = 1; off < 64; off <<= 1) {
    s += __shfl_xor(s, off);
    q += __shfl_xor(q, off);
  }
  float m = s * (1.f / 128.f);
  float var = q * (1.f / 128.f) - m * m;
  float rs = rsqrtf(var + 1e-5f);
  float2 gg = *(const float2*)(g + lane * 2);
  float2 bb = *(const float2*)(b + lane * 2);
  float2 o;
  o.x = (v.x - m) * rs * gg.x + bb.x;
  o.y = (v.y - m) * rs * gg.y + bb.y;
  *(float2*)(out + base) = o;
}

// ---- linear-attn phase 1: partial kv/ksum per (b,h,chunk of 64 rows) ----
// 512 blocks = bh*8 + ch. Same LDS-staged inner loop as before, 8 iterations.
__global__ __launch_bounds__(256) void attn_kv_part_k(
    const float* __restrict__ qkv, float* __restrict__ pkv, float* __restrict__ pks) {
  int bx = blockIdx.x;  // bh*8 + ch
  int bh = bx >> 3, ch = bx & 7;
  int b = bh >> 2, h = bh & 3;
  int t = threadIdx.x;
  int d = t >> 3, e4 = (t & 7) << 2;
  __shared__ float ks[8][32], vs[8][32];
  float a0 = 0, a1 = 0, a2 = 0, a3 = 0, ksa = 0;
  size_t base = (size_t)b * 512 * 384;
  int l0 = ch * 64;
  for (int lc = l0; lc < l0 + 64; lc += 8) {
    #pragma unroll
    for (int i = 0; i < 2; ++i) {
      int j = i * 256 + t;  // 512 values: 8 rows x (k[32] | v[32])
      int rl = j >> 6, rem = j & 63, half = rem >> 5, col = rem & 31;
      float val = qkv[base + (size_t)(lc + rl) * 384 + 128 + half * 128 + h * 32 + col];
      if (half) vs[rl][col] = val; else ks[rl][col] = val;
    }
    __syncthreads();
    #pragma unroll
    for (int r = 0; r < 8; ++r) {
      float kd = ks[r][d];
      if ((t & 7) == 0) ksa += kd;
      a0 = fmaf(kd, vs[r][e4 + 0], a0);
      a1 = fmaf(kd, vs[r][e4 + 1], a1);
      a2 = fmaf(kd, vs[r][e4 + 2], a2);
      a3 = fmaf(kd, vs[r][e4 + 3], a3);
    }
    __syncthreads();
  }
  float* kvp = pkv + (size_t)bx * 1024 + d * 32 + e4;
  kvp[0] = a0; kvp[1] = a1; kvp[2] = a2; kvp[3] = a3;
  if ((t & 7) == 0) pks[bx * 32 + d] = ksa;
}

// ---- linear-attn phase 2: reduce 8 chunk partials -> kv[b,h], ksum[b,h] ----
__global__ __launch_bounds__(256) void attn_kv_red_k(
    const float* __restrict__ pkv, const float* __restrict__ pks,
    float* __restrict__ kv, float* __restrict__ ksum) {
  int bh = blockIdx.x;
  int t = threadIdx.x;
  float4 acc = make_float4(0.f, 0.f, 0.f, 0.f);
  #pragma unroll
  for (int ch = 0; ch < 8; ++ch) {
    const float4 v = *(const float4*)(pkv + ((size_t)(bh * 8 + ch)) * 1024 + t * 4);
    acc.x += v.x; acc.y += v.y; acc.z += v.z; acc.w += v.w;
  }
  *(float4*)(kv + (size_t)bh * 1024 + t * 4) = acc;
  if (t < 32) {
    float s = 0.f;
    #pragma unroll
    for (int ch = 0; ch < 8; ++ch) s += pks[(bh * 8 + ch) * 32 + t];
    ksum[bh * 32 + t] = s;
  }
}

// ---------------- linear-attn apply ----------------
__global__ __launch_bounds__(128) void attn_apply_k(
    const float* __restrict__ qkv, const float* __restrict__ kv,
    const float* __restrict__ ksum, float* __restrict__ attn) {
  int row = blockIdx.x;
  int t = threadIdx.x, h = t >> 5, e = t & 31;
  int b = row >> 9;
  const float* qr = qkv + (size_t)row * 384 + h * 32;
  const float* kvp = kv + (size_t)(b * 4 + h) * 1024;
  const float* ksp = ksum + (b * 4 + h) * 32;
  float num = 0.f, den = 0.f;
  #pragma unroll 8
  for (int d = 0; d < 32; ++d) {
    float qd = qr[d];
    num = fmaf(qd, kvp[d * 32 + e], num);
    den = fmaf(qd, ksp[d], den);
  }
  attn[(size_t)row * 128 + t] = num / (den + 1e-6f);
}

// -------- mamba depthwise causal conv + silu; dt softplus; dA = exp(dt*A) --------
__global__ __launch_bounds__(320) void mamba_conv_k(
    const float* __restrict__ zx, const float* __restrict__ cw,
    const float* __restrict__ cb, const float* __restrict__ dtb,
    const float* __restrict__ Alog,
    float* __restrict__ xc, float* __restrict__ dt, float* __restrict__ da) {
  int row = blockIdx.x;  // b*512 + l
  int c = threadIdx.x;   // 0..319
  int l = row & 511;
  float acc = cb[c];
  #pragma unroll
  for (int i = 0; i < 4; ++i) {
    int dl = i - 3;
    if (l + dl >= 0)
      acc += zx[(size_t)(row + dl) * 584 + 256 + c] * cw[c * 4 + i];
  }
  float s = acc / (1.f + __expf(-acc));  // silu
  xc[(size_t)row * 320 + c] = s;
  if (c < 8) {
    float r = zx[(size_t)row * 584 + 576 + c] + dtb[c];
    float dtv = fmaxf(r, 0.f) + log1pf(__expf(-fabsf(r)));  // softplus
    dt[(size_t)row * 8 + c] = dtv;
    float Ah = -__expf(Alog[c]);
    da[(size_t)row * 8 + c] = __expf(dtv * Ah);
  }
}

// ---------------- SSM scan v3: chunked parallel scan ----------------
__global__ __launch_bounds__(256) void scan_chunk_k(
    const float* __restrict__ xc, const float* __restrict__ dt,
    const float* __restrict__ da, const float* __restrict__ Dsk,
    float* __restrict__ y, float* __restrict__ ech,
    float* __restrict__ ach, float* __restrict__ cum) {
  int bx = blockIdx.x;  // h*256 + b*16 + c
  int h = bx >> 8, b = (bx >> 4) & 15, c = bx & 15;
  int t = threadIdx.x;
  int nh = t & 7, p = t >> 3;
  float Dh = Dsk[h];
  float h0 = 0.f, h1 = 0.f, h2 = 0.f, h3 = 0.f, cp = 1.f;
  size_t row = (size_t)b * 512 + c * 32;
  const float* dtp = dt + row * 8 + h;
  const float* dap = da + row * 8 + h;
  const float* xp = xc + row * 320 + h * 32 + p;
  const float* Bp = xc + row * 320 + 256 + nh * 4;
  const float* Cp = xc + row * 320 + 288 + nh * 4;
  float* yp = y + row * 256 + h * 32 + p;
  int bh = b * 8 + h;
  float* cpo = cum + (size_t)bh * 512 + c * 32;
  #pragma unroll 4
  for (int l = 0; l < 32; ++l) {
    float dtv = dtp[l * 8];
    float dav = dap[l * 8];
    float xs = xp[(size_t)l * 320];
    float4 Bq = *(const float4*)(Bp + (size_t)l * 320);
    float4 Cq = *(const float4*)(Cp + (size_t)l * 320);
    float ux = dtv * xs;
    h0 = fmaf(h0, dav, ux * Bq.x);
    h1 = fmaf(h1, dav, ux * Bq.y);
    h2 = fmaf(h2, dav, ux * Bq.z);
    h3 = fmaf(h3, dav, ux * Bq.w);
    float yv = Cq.x * h0;
    yv = fmaf(Cq.y, h1, yv);
    yv = fmaf(Cq.z, h2, yv);
    yv = fmaf(Cq.w, h3, yv);
    yv += __shfl_xor(yv, 1);
    yv += __shfl_xor(yv, 2);
    yv += __shfl_xor(yv, 4);
    cp *= dav;
    if (nh == 0) yp[(size_t)l * 256] = yv + Dh * xs;
    if (t == 0) cpo[l] = cp;
  }
  *(float4*)(ech + ((size_t)(bh * 16 + c)) * 1024 + p * 32 + nh * 4) =
      make_float4(h0, h1, h2, h3);
  if (t == 0) ach[bh * 16 + c] = cp;
}

// Phase BC: serial chunk-combine (16 steps) + correction.
__global__ __launch_bounds__(1024) void scan_fix_k(
    const float* __restrict__ xc, const float* __restrict__ cum,
    const float* __restrict__ ech, const float* __restrict__ ach,
    float* __restrict__ y) {
  int bh = blockIdx.x;
  int b = bh >> 3, h = bh & 7;
  int t = threadIdx.x;
  int pq = t >> 5, nq = t & 31;
  int lw = t >> 5, pp = t & 31;
  __shared__ float Hs[32][33];
  float Hreg = 0.f;
  const size_t row0 = (size_t)b * 512;
  for (int c = 0; c < 16; ++c) {
    Hs[pq][nq] = Hreg;
    __syncthreads();
    float e = ech[((size_t)(bh * 16 + c)) * 1024 + t];
    float a = ach[bh * 16 + c];
    Hreg = fmaf(Hreg, a, e);
    if (c) {
      int l = c * 32 + lw;
      size_t row = row0 + l;
      const float* Cr = xc + row * 320 + 288;
      float dot = 0.f;
      #pragma unroll 8
      for (int n = 0; n < 32; ++n) dot = fmaf(Cr[n], Hs[pp][n], dot);
      float cd = cum[(size_t)bh * 512 + l];
      y[row * 256 + h * 32 + pp] += cd * dot;
    }
    __syncthreads();
  }
}

// ---------------- y gating: y *= silu(zg); RMS(256) * mnorm_w ----------------
__global__ __launch_bounds__(256) void gate_rms_k(
    float* __restrict__ y, const float* __restrict__ zx, const float* __restrict__ mw) {
  int row = blockIdx.x;
  int c = threadIdx.x;
  float zg = zx[(size_t)row * 584 + c];
  float val = y[(size_t)row * 256 + c] * (zg / (1.f + __expf(-zg)));
  float sq = val * val;
  #pragma unroll
  for (int off = 1; off < 64; off <<= 1) sq += __shfl_xor(sq, off);
  __shared__ float ps[4];
  if ((c & 63) == 0) ps[c >> 6] = sq;
  __syncthreads();
  float tot = ps[0] + ps[1] + ps[2] + ps[3];
  y[(size_t)row * 256 + c] = val * rsqrtf(tot * (1.f / 256.f) + 1e-6f) * mw[c];
}

// ---------------- final: RMS(t + residual) then LN ----------------
__global__ __launch_bounds__(256) void final_k(
    const float* __restrict__ t, const float* __restrict__ hres,
    const float* __restrict__ rmsw, const float* __restrict__ g,
    const float* __restrict__ b, float* __restrict__ out) {
  int r = (blockIdx.x << 2) + (threadIdx.x >> 6);
  int lane = threadIdx.x & 63;
  size_t base = (size_t)r * 128 + lane * 2;
  float2 tv = *(const float2*)(t + base);
  float2 hv = *(const float2*)(hres + base);
  float vx = tv.x + hv.x, vy = tv.y + hv.y;
  float sq = vx * vx + vy * vy;
  #pragma unroll
  for (int off = 1; off < 64; off <<= 1) sq += __shfl_xor(sq, off);
  float rs = rsqrtf(sq * (1.f / 128.f) + 1e-6f);
  float rx = vx * rs * rmsw[lane * 2], ry = vy * rs * rmsw[lane * 2 + 1];
  float s = rx + ry, q2 = rx * rx + ry * ry;
  #pragma unroll
  for (int off = 1; off < 64; off <<= 1) {
    s += __shfl_xor(s, off);
    q2 += __shfl_xor(q2, off);
  }
  float m = s * (1.f / 128.f), var = q2 * (1.f / 128.f) - m * m;
  float inv = rsqrtf(var + 1e-5f);
  float2 o;
  o.x = (rx - m) * inv * g[lane * 2] + b[lane * 2];
  o.y = (ry - m) * inv * g[lane * 2 + 1] + b[lane * 2 + 1];
  *(float2*)(out + base) = o;
}

extern "C" void kernel_launch(void* const* d_in, const int* in_sizes, int n_in,
                              void* d_out, int out_size, void* d_ws, size_t ws_size,
                              hipStream_t stream) {
  const float* x      = (const float*)d_in[0];
  const float* w_in   = (const float*)d_in[1];
  const float* b_in   = (const float*)d_in[2];
  const float* c1w    = (const float*)d_in[3];
  const float* bn1g   = (const float*)d_in[4];
  const float* bn1b   = (const float*)d_in[5];
  const float* c2w    = (const float*)d_in[6];
  const float* bn2g   = (const float*)d_in[7];
  const float* bn2b   = (const float*)d_in[8];
  const float* ln1g   = (const float*)d_in[9];
  const float* ln1b   = (const float*)d_in[10];
  const float* wq     = (const float*)d_in[11];
  const float* wk     = (const float*)d_in[12];
  const float* wv     = (const float*)d_in[13];
  const float* wo     = (const float*)d_in[14];
  const float* bo     = (const float*)d_in[15];
  const float* ln2g   = (const float*)d_in[16];
  const float* ln2b   = (const float*)d_in[17];
  const float* ff1w   = (const float*)d_in[18];
  const float* ff1b   = (const float*)d_in[19];
  const float* ff2w   = (const float*)d_in[20];
  const float* ff2b   = (const float*)d_in[21];
  const float* ipw    = (const float*)d_in[22];
  const float* cw     = (const float*)d_in[23];
  const float* cb     = (const float*)d_in[24];
  const float* dtb    = (const float*)d_in[25];
  const float* Alog   = (const float*)d_in[26];
  const float* Dsk    = (const float*)d_in[27];
  const float* mnw    = (const float*)d_in[28];
  const float* outw   = (const float*)d_in[29];
  const float* rmsw   = (const float*)d_in[30];
  const float* olng   = (const float*)d_in[31];
  const float* olnb   = (const float*)d_in[32];

  float* ws = (float*)d_ws;
  const size_t MG = 1u << 20;
  // small region (< 1M floats)
  float* W1   = ws + 0;        // 16384
  float* W2   = ws + 16384;    // 65536
  float* SC   = ws + 81920;    // 512
  float* BQKV = ws + 82432;    // 49152
  float* KV   = ws + 131584;   // 65536
  float* KS   = ws + 197120;   // 2048
  float* DT   = ws + 199168;   // 65536
  float* DA   = ws + 264704;   // 65536
  float* CUM  = ws + 330240;   // 65536
  float* ACH  = ws + 395776;   // 2048
  float* PKV  = ws + 397824;   // 524288 (attn kv partials, live only within attn)
  float* PKS  = ws + 922112;   // 16384
  // big region R at 1M..~5.57M, time-multiplexed
  float* R    = ws + MG;
  float* OUT1 = R;                       // 4M  (gemm1 -> gemm2)
  float* QKV  = R;                       // 3M  (qkv -> attn)
  float* ATTN = R + 3 * MG;              // 1M
  float* MID  = R;                       // 2M  (ffn mid)
  float* ZX   = R;                       // 4.57M (in_proj -> gate)
  float* ECH  = ws + 5 * MG + 786432;    // 2M at 5.75M..7.75M (scan chunk states)
  float* H    = ws + 8 * MG;             // 1M, persistent residual
  float* ATMP = ws + 9 * MG;             // 1M, ln outs / final pre-add
  float* XC   = ws + 10 * MG;            // 2.56M
  float* Y    = ws + 12 * MG + 786432;   // 2M at 12.75M..14.75M
  float* out  = (float*)d_out;

  prep_k<<<513, 256, 0, stream>>>(w_in, b_in, c1w, bn1g, bn1b, c2w, bn2g, bn2b,
                                  wq, wk, wv, W1, W2, SC, BQKV);
  // fused (x@w_in -> conv1 -> bn -> gelu):  (32768x128)@(128x128)
  gemm_k<EPI_BNGELU, 64><<<dim3(512, 1), 256, 0, stream>>>(
      x, W1, OUT1, nullptr, SC, SC + 128, 32768, 128, 128);
  // conv2 -> bn -> gelu: (8192x512)@(512x128)
  gemm_k<EPI_BNGELU, 32><<<dim3(256, 1), 256, 0, stream>>>(
      OUT1, W2, H, nullptr, SC + 256, SC + 384, 8192, 128, 512);
  ln_rows_k<<<2048, 256, 0, stream>>>(H, ATMP, ln1g, ln1b);
  // fused q|k|v projection, elu+1 on q,k
  gemm_k<EPI_QKV, 32><<<dim3(256, 3), 256, 0, stream>>>(
      ATMP, BQKV, QKV, nullptr, nullptr, nullptr, 8192, 384, 128);
  attn_kv_part_k<<<512, 256, 0, stream>>>(QKV, PKV, PKS);
  attn_kv_red_k<<<64, 256, 0, stream>>>(PKV, PKS, KV, KS);
  attn_apply_k<<<8192, 128, 0, stream>>>(QKV, KV, KS, ATTN);
  // h += attn@wo + bo
  gemm_k<EPI_RESBIAS, 32><<<dim3(256, 1), 256, 0, stream>>>(
      ATTN, wo, H, H, bo, nullptr, 8192, 128, 128);
  ln_rows_k<<<2048, 256, 0, stream>>>(H, ATMP, ln2g, ln2b);
  gemm_k<EPI_BIASGELU, 32><<<dim3(256, 2), 256, 0, stream>>>(
      ATMP, ff1w, MID, nullptr, ff1b, nullptr, 8192, 256, 128);
  gemm_k<EPI_RESBIAS, 32><<<dim3(256, 1), 256, 0, stream>>>(
      MID, ff2w, H, H, ff2b, nullptr, 8192, 128, 256);
  // in_proj: (8192x128)@(128x584)
  gemm_k<EPI_NONE, 32><<<dim3(256, 5), 256, 0, stream>>>(
      H, ipw, ZX, nullptr, nullptr, nullptr, 8192, 584, 128);
  mamba_conv_k<<<8192, 320, 0, stream>>>(ZX, cw, cb, dtb, Alog, XC, DT, DA);
  scan_chunk_k<<<2048, 256, 0, stream>>>(XC, DT, DA, Dsk, Y, ECH, ACH, CUM);
  scan_fix_k<<<128, 1024, 0, stream>>>(XC, CUM, ECH, ACH, Y);
  gate_rms_k<<<8192, 256, 0, stream>>>(Y, ZX, mnw);
  gemm_k<EPI_NONE, 32><<<dim3(256, 1), 256, 0, stream>>>(
      Y, outw, ATMP, nullptr, nullptr, nullptr, 8192, 128, 256);
  final_k<<<2048, 256, 0, stream>>>(ATMP, H, rmsw, olng, olnb, out);
  (void)in_sizes; (void)n_in; (void)out_size; (void)ws_size;
}

// Round 11
// 411.736 us; speedup vs baseline: 1.5702x; 1.0285x over previous
//
#include <hip/hip_runtime.h>
#include <cstdint>
#include <cstddef>

// Shapes
// B=16, L=16384, E=16, H=128, NH=4, DH=32, FF=256, D_STATE=32, HEADDIM=32
// D_INNER=256, NHEADS=8, CONV_DIM=320, DCONV=4, LC=512, ROWS=B*LC=8192

#define EPI_NONE 0
#define EPI_BNGELU 1
#define EPI_QKV 2
#define EPI_RESBIAS 3
#define EPI_BIASGELU 4
#define EPI_BNGELU_LN 5
#define EPI_RESBIAS_LN 6
#define EPI_FINAL 7

static __device__ __forceinline__ float gelu_f(float x) {
  float t = tanhf(0.7978845608028654f * (x + 0.044715f * x * x * x));
  return 0.5f * x * (1.0f + t);
}

// ---------------- prep: effective conv weights, BN folding, qkv pack ----------------
__global__ __launch_bounds__(256) void prep_k(
    const float* __restrict__ w_in, const float* __restrict__ b_in,
    const float* __restrict__ c1w, const float* __restrict__ bn1g,
    const float* __restrict__ bn1b, const float* __restrict__ c2w,
    const float* __restrict__ bn2g, const float* __restrict__ bn2b,
    const float* __restrict__ wq, const float* __restrict__ wk,
    const float* __restrict__ wv,
    float* __restrict__ W1, float* __restrict__ W2,
    float* __restrict__ sc, float* __restrict__ Bqkv) {
  int idx = blockIdx.x * 256 + threadIdx.x;
  const float inv = rsqrtf(1.0f + 1e-5f);
  if (idx < 16384) {
    int k = idx >> 7, c = idx & 127;
    int e = k & 15, i = k >> 4;
    float s = 0.f;
    #pragma unroll 4
    for (int cin = 0; cin < 128; ++cin)
      s += w_in[e * 128 + cin] * c1w[c * 1024 + cin * 8 + i];
    W1[idx] = s;
  } else if (idx < 16384 + 65536) {
    int j = idx - 16384;
    int k = j >> 7, c = j & 127;
    int i = k >> 7, cin = k & 127;
    W2[j] = c2w[c * 512 + cin * 4 + i];
  } else if (idx < 16384 + 65536 + 128) {
    int c = idx - (16384 + 65536);
    float b1 = 0.f;
    for (int cin = 0; cin < 128; ++cin) {
      float bi = b_in[cin];
      #pragma unroll
      for (int i = 0; i < 8; ++i) b1 += bi * c1w[c * 1024 + cin * 8 + i];
    }
    float s1 = bn1g[c] * inv;
    sc[c] = s1;
    sc[128 + c] = b1 * s1 + bn1b[c];
    sc[256 + c] = bn2g[c] * inv;
    sc[384 + c] = bn2b[c];
  } else {
    int j = idx - (16384 + 65536 + 128);
    if (j < 128 * 384) {
      int k = j / 384, n = j % 384;
      float v = (n < 128) ? wq[k * 128 + n]
              : (n < 256) ? wk[k * 128 + (n - 128)]
                          : wv[k * 128 + (n - 256)];
      Bqkv[j] = v;
    }
  }
}

// ---------------- generic fp32 GEMM, row-major, BM x 128 x BK=32, 256 thr ----------------
// LN-fused epilogues (EPI_*_LN, EPI_FINAL) require N == BN == 128 (full row per block):
// a row lives in 32 contiguous lanes (same tr, tc=0..31) -> shfl_xor(1..16) row-reduce.
template <int EPI, int BM>
__global__ __launch_bounds__(256) void gemm_k(
    const float* __restrict__ A, const float* __restrict__ B,
    float* __restrict__ C, const float* __restrict__ Cres,
    const float* __restrict__ v0, const float* __restrict__ v1,
    const float* __restrict__ g, const float* __restrict__ bb,
    float* __restrict__ C2,
    int M, int N, int K) {
  constexpr int RT = BM / 8;
  __shared__ float As[BM][33];
  __shared__ float Bs[32][128];
  const int tid = threadIdx.x;
  const int row0 = blockIdx.x * BM;
  const int n0 = blockIdx.y * 128;
  const int tr = tid >> 5, tc = tid & 31;
  float acc[RT][4];
  #pragma unroll
  for (int i = 0; i < RT; ++i)
    for (int j = 0; j < 4; ++j) acc[i][j] = 0.f;

  for (int k0 = 0; k0 < K; k0 += 32) {
    #pragma unroll
    for (int i = 0; i < BM / 32; ++i) {
      int j = i * 256 + tid;
      int m = j >> 3, k4 = (j & 7) << 2;
      const float4 av = *(const float4*)(A + (size_t)(row0 + m) * K + k0 + k4);
      As[m][k4] = av.x; As[m][k4 + 1] = av.y; As[m][k4 + 2] = av.z; As[m][k4 + 3] = av.w;
    }
    #pragma unroll
    for (int i = 0; i < 4; ++i) {
      int j = i * 256 + tid;
      int kk = j >> 5, c4 = (j & 31) << 2;
      float4 bv = make_float4(0.f, 0.f, 0.f, 0.f);
      if (n0 + c4 < N) bv = *(const float4*)(B + (size_t)(k0 + kk) * N + n0 + c4);
      *(float4*)&Bs[kk][c4] = bv;
    }
    __syncthreads();
    #pragma unroll
    for (int kk = 0; kk < 32; ++kk) {
      const float4 bv = *(const float4*)&Bs[kk][tc << 2];
      #pragma unroll
      for (int i = 0; i < RT; ++i) {
        float a = As[tr * RT + i][kk];
        acc[i][0] = fmaf(a, bv.x, acc[i][0]);
        acc[i][1] = fmaf(a, bv.y, acc[i][1]);
        acc[i][2] = fmaf(a, bv.z, acc[i][2]);
        acc[i][3] = fmaf(a, bv.w, acc[i][3]);
      }
    }
    __syncthreads();
  }

  int cc = n0 + (tc << 2);
  if (cc >= N) return;
  #pragma unroll
  for (int i = 0; i < RT; ++i) {
    int rr = row0 + tr * RT + i;
    float v[4];
    #pragma unroll
    for (int jj = 0; jj < 4; ++jj) {
      float x = acc[i][jj];
      if (EPI == EPI_BNGELU || EPI == EPI_BNGELU_LN)
        x = gelu_f(x * v0[cc + jj] + v1[cc + jj]);
      else if (EPI == EPI_QKV) { if (cc + jj < 256) x = (x > 0.f) ? x + 1.f : __expf(x); }
      else if (EPI == EPI_RESBIAS || EPI == EPI_RESBIAS_LN)
        x = Cres[(size_t)rr * N + cc + jj] + x + v0[cc + jj];
      else if (EPI == EPI_BIASGELU) x = gelu_f(x + v0[cc + jj]);
      else if (EPI == EPI_FINAL) x = x + Cres[(size_t)rr * N + cc + jj];
      v[jj] = x;
    }
    if (EPI != EPI_FINAL)
      *(float4*)(C + (size_t)rr * N + cc) = make_float4(v[0], v[1], v[2], v[3]);
    if (EPI == EPI_BNGELU_LN || EPI == EPI_RESBIAS_LN) {
      float s = v[0] + v[1] + v[2] + v[3];
      float q = v[0]*v[0] + v[1]*v[1] + v[2]*v[2] + v[3]*v[3];
      #pragma unroll
      for (int off = 1; off < 32; off <<= 1) {
        s += __shfl_xor(s, off);
        q += __shfl_xor(q, off);
      }
      float m = s * (1.f / 128.f);
      float var = q * (1.f / 128.f) - m * m;
      float ivr = rsqrtf(var + 1e-5f);
      float o[4];
      #pragma unroll
      for (int jj = 0; jj < 4; ++jj)
        o[jj] = (v[jj] - m) * ivr * g[cc + jj] + bb[cc + jj];
      *(float4*)(C2 + (size_t)rr * N + cc) = make_float4(o[0], o[1], o[2], o[3]);
    } else if (EPI == EPI_FINAL) {
      // RMS(128) with weight v0, then LN with g, bb -> C
      float q = v[0]*v[0] + v[1]*v[1] + v[2]*v[2] + v[3]*v[3];
      #pragma unroll
      for (int off = 1; off < 32; off <<= 1) q += __shfl_xor(q, off);
      float rs = rsqrtf(q * (1.f / 128.f) + 1e-6f);
      float r[4];
      #pragma unroll
      for (int jj = 0; jj < 4; ++jj) r[jj] = v[jj] * rs * v0[cc + jj];
      float s = r[0] + r[1] + r[2] + r[3];
      float q2 = r[0]*r[0] + r[1]*r[1] + r[2]*r[2] + r[3]*r[3];
      #pragma unroll
      for (int off = 1; off < 32; off <<= 1) {
        s += __shfl_xor(s, off);
        q2 += __shfl_xor(q2, off);
      }
      float m = s * (1.f / 128.f);
      float var = q2 * (1.f / 128.f) - m * m;
      float ivr = rsqrtf(var + 1e-5f);
      float o[4];
      #pragma unroll
      for (int jj = 0; jj < 4; ++jj)
        o[jj] = (r[jj] - m) * ivr * g[cc + jj] + bb[cc + jj];
      *(float4*)(C + (size_t)rr * N + cc) = make_float4(o[0], o[1], o[2], o[3]);
    }
  }
}

// ---- linear-attn phase 1: partial kv/ksum per (b,h,chunk of 64 rows) ----
__global__ __launch_bounds__(256) void attn_kv_part_k(
    const float* __restrict__ qkv, float* __restrict__ pkv, float* __restrict__ pks) {
  int bx = blockIdx.x;  // bh*8 + ch
  int bh = bx >> 3, ch = bx & 7;
  int b = bh >> 2, h = bh & 3;
  int t = threadIdx.x;
  int d = t >> 3, e4 = (t & 7) << 2;
  __shared__ float ks[8][32], vs[8][32];
  float a0 = 0, a1 = 0, a2 = 0, a3 = 0, ksa = 0;
  size_t base = (size_t)b * 512 * 384;
  int l0 = ch * 64;
  for (int lc = l0; lc < l0 + 64; lc += 8) {
    #pragma unroll
    for (int i = 0; i < 2; ++i) {
      int j = i * 256 + t;
      int rl = j >> 6, rem = j & 63, half = rem >> 5, col = rem & 31;
      float val = qkv[base + (size_t)(lc + rl) * 384 + 128 + half * 128 + h * 32 + col];
      if (half) vs[rl][col] = val; else ks[rl][col] = val;
    }
    __syncthreads();
    #pragma unroll
    for (int r = 0; r < 8; ++r) {
      float kd = ks[r][d];
      if ((t & 7) == 0) ksa += kd;
      a0 = fmaf(kd, vs[r][e4 + 0], a0);
      a1 = fmaf(kd, vs[r][e4 + 1], a1);
      a2 = fmaf(kd, vs[r][e4 + 2], a2);
      a3 = fmaf(kd, vs[r][e4 + 3], a3);
    }
    __syncthreads();
  }
  float* kvp = pkv + (size_t)bx * 1024 + d * 32 + e4;
  kvp[0] = a0; kvp[1] = a1; kvp[2] = a2; kvp[3] = a3;
  if ((t & 7) == 0) pks[bx * 32 + d] = ksa;
}

// ---- linear-attn phase 2: reduce 8 chunk partials -> kv[b,h], ksum[b,h] ----
__global__ __launch_bounds__(256) void attn_kv_red_k(
    const float* __restrict__ pkv, const float* __restrict__ pks,
    float* __restrict__ kv, float* __restrict__ ksum) {
  int bh = blockIdx.x;
  int t = threadIdx.x;
  float4 acc = make_float4(0.f, 0.f, 0.f, 0.f);
  #pragma unroll
  for (int ch = 0; ch < 8; ++ch) {
    const float4 v = *(const float4*)(pkv + ((size_t)(bh * 8 + ch)) * 1024 + t * 4);
    acc.x += v.x; acc.y += v.y; acc.z += v.z; acc.w += v.w;
  }
  *(float4*)(kv + (size_t)bh * 1024 + t * 4) = acc;
  if (t < 32) {
    float s = 0.f;
    #pragma unroll
    for (int ch = 0; ch < 8; ++ch) s += pks[(bh * 8 + ch) * 32 + t];
    ksum[bh * 32 + t] = s;
  }
}

// ---------------- linear-attn apply ----------------
__global__ __launch_bounds__(128) void attn_apply_k(
    const float* __restrict__ qkv, const float* __restrict__ kv,
    const float* __restrict__ ksum, float* __restrict__ attn) {
  int row = blockIdx.x;
  int t = threadIdx.x, h = t >> 5, e = t & 31;
  int b = row >> 9;
  const float* qr = qkv + (size_t)row * 384 + h * 32;
  const float* kvp = kv + (size_t)(b * 4 + h) * 1024;
  const float* ksp = ksum + (b * 4 + h) * 32;
  float num = 0.f, den = 0.f;
  #pragma unroll 8
  for (int d = 0; d < 32; ++d) {
    float qd = qr[d];
    num = fmaf(qd, kvp[d * 32 + e], num);
    den = fmaf(qd, ksp[d], den);
  }
  attn[(size_t)row * 128 + t] = num / (den + 1e-6f);
}

// -------- mamba depthwise causal conv + silu; dt softplus; dA = exp(dt*A) --------
__global__ __launch_bounds__(320) void mamba_conv_k(
    const float* __restrict__ zx, const float* __restrict__ cw,
    const float* __restrict__ cb, const float* __restrict__ dtb,
    const float* __restrict__ Alog,
    float* __restrict__ xc, float* __restrict__ dt, float* __restrict__ da) {
  int row = blockIdx.x;  // b*512 + l
  int c = threadIdx.x;   // 0..319
  int l = row & 511;
  float acc = cb[c];
  #pragma unroll
  for (int i = 0; i < 4; ++i) {
    int dl = i - 3;
    if (l + dl >= 0)
      acc += zx[(size_t)(row + dl) * 584 + 256 + c] * cw[c * 4 + i];
  }
  float s = acc / (1.f + __expf(-acc));  // silu
  xc[(size_t)row * 320 + c] = s;
  if (c < 8) {
    float r = zx[(size_t)row * 584 + 576 + c] + dtb[c];
    float dtv = fmaxf(r, 0.f) + log1pf(__expf(-fabsf(r)));  // softplus
    dt[(size_t)row * 8 + c] = dtv;
    float Ah = -__expf(Alog[c]);
    da[(size_t)row * 8 + c] = __expf(dtv * Ah);
  }
}

// ---------------- SSM scan: chunked parallel scan ----------------
__global__ __launch_bounds__(256) void scan_chunk_k(
    const float* __restrict__ xc, const float* __restrict__ dt,
    const float* __restrict__ da, const float* __restrict__ Dsk,
    float* __restrict__ y, float* __restrict__ ech,
    float* __restrict__ ach, float* __restrict__ cum) {
  int bx = blockIdx.x;  // h*256 + b*16 + c
  int h = bx >> 8, b = (bx >> 4) & 15, c = bx & 15;
  int t = threadIdx.x;
  int nh = t & 7, p = t >> 3;
  float Dh = Dsk[h];
  float h0 = 0.f, h1 = 0.f, h2 = 0.f, h3 = 0.f, cp = 1.f;
  size_t row = (size_t)b * 512 + c * 32;
  const float* dtp = dt + row * 8 + h;
  const float* dap = da + row * 8 + h;
  const float* xp = xc + row * 320 + h * 32 + p;
  const float* Bp = xc + row * 320 + 256 + nh * 4;
  const float* Cp = xc + row * 320 + 288 + nh * 4;
  float* yp = y + row * 256 + h * 32 + p;
  int bh = b * 8 + h;
  float* cpo = cum + (size_t)bh * 512 + c * 32;
  #pragma unroll 4
  for (int l = 0; l < 32; ++l) {
    float dtv = dtp[l * 8];
    float dav = dap[l * 8];
    float xs = xp[(size_t)l * 320];
    float4 Bq = *(const float4*)(Bp + (size_t)l * 320);
    float4 Cq = *(const float4*)(Cp + (size_t)l * 320);
    float ux = dtv * xs;
    h0 = fmaf(h0, dav, ux * Bq.x);
    h1 = fmaf(h1, dav, ux * Bq.y);
    h2 = fmaf(h2, dav, ux * Bq.z);
    h3 = fmaf(h3, dav, ux * Bq.w);
    float yv = Cq.x * h0;
    yv = fmaf(Cq.y, h1, yv);
    yv = fmaf(Cq.z, h2, yv);
    yv = fmaf(Cq.w, h3, yv);
    yv += __shfl_xor(yv, 1);
    yv += __shfl_xor(yv, 2);
    yv += __shfl_xor(yv, 4);
    cp *= dav;
    if (nh == 0) yp[(size_t)l * 256] = yv + Dh * xs;
    if (t == 0) cpo[l] = cp;
  }
  *(float4*)(ech + ((size_t)(bh * 16 + c)) * 1024 + p * 32 + nh * 4) =
      make_float4(h0, h1, h2, h3);
  if (t == 0) ach[bh * 16 + c] = cp;
}

// Phase BC: serial chunk-combine (16 steps) + correction.
__global__ __launch_bounds__(1024) void scan_fix_k(
    const float* __restrict__ xc, const float* __restrict__ cum,
    const float* __restrict__ ech, const float* __restrict__ ach,
    float* __restrict__ y) {
  int bh = blockIdx.x;
  int b = bh >> 3, h = bh & 7;
  int t = threadIdx.x;
  int pq = t >> 5, nq = t & 31;
  int lw = t >> 5, pp = t & 31;
  __shared__ float Hs[32][33];
  float Hreg = 0.f;
  const size_t row0 = (size_t)b * 512;
  for (int c = 0; c < 16; ++c) {
    Hs[pq][nq] = Hreg;
    __syncthreads();
    float e = ech[((size_t)(bh * 16 + c)) * 1024 + t];
    float a = ach[bh * 16 + c];
    Hreg = fmaf(Hreg, a, e);
    if (c) {
      int l = c * 32 + lw;
      size_t row = row0 + l;
      const float* Cr = xc + row * 320 + 288;
      float dot = 0.f;
      #pragma unroll 8
      for (int n = 0; n < 32; ++n) dot = fmaf(Cr[n], Hs[pp][n], dot);
      float cd = cum[(size_t)bh * 512 + l];
      y[row * 256 + h * 32 + pp] += cd * dot;
    }
    __syncthreads();
  }
}

// ---------------- y gating: y *= silu(zg); RMS(256) * mnorm_w ----------------
__global__ __launch_bounds__(256) void gate_rms_k(
    float* __restrict__ y, const float* __restrict__ zx, const float* __restrict__ mw) {
  int row = blockIdx.x;
  int c = threadIdx.x;
  float zg = zx[(size_t)row * 584 + c];
  float val = y[(size_t)row * 256 + c] * (zg / (1.f + __expf(-zg)));
  float sq = val * val;
  #pragma unroll
  for (int off = 1; off < 64; off <<= 1) sq += __shfl_xor(sq, off);
  __shared__ float ps[4];
  if ((c & 63) == 0) ps[c >> 6] = sq;
  __syncthreads();
  float tot = ps[0] + ps[1] + ps[2] + ps[3];
  y[(size_t)row * 256 + c] = val * rsqrtf(tot * (1.f / 256.f) + 1e-6f) * mw[c];
}

extern "C" void kernel_launch(void* const* d_in, const int* in_sizes, int n_in,
                              void* d_out, int out_size, void* d_ws, size_t ws_size,
                              hipStream_t stream) {
  const float* x      = (const float*)d_in[0];
  const float* w_in   = (const float*)d_in[1];
  const float* b_in   = (const float*)d_in[2];
  const float* c1w    = (const float*)d_in[3];
  const float* bn1g   = (const float*)d_in[4];
  const float* bn1b   = (const float*)d_in[5];
  const float* c2w    = (const float*)d_in[6];
  const float* bn2g   = (const float*)d_in[7];
  const float* bn2b   = (const float*)d_in[8];
  const float* ln1g   = (const float*)d_in[9];
  const float* ln1b   = (const float*)d_in[10];
  const float* wq     = (const float*)d_in[11];
  const float* wk     = (const float*)d_in[12];
  const float* wv     = (const float*)d_in[13];
  const float* wo     = (const float*)d_in[14];
  const float* bo     = (const float*)d_in[15];
  const float* ln2g   = (const float*)d_in[16];
  const float* ln2b   = (const float*)d_in[17];
  const float* ff1w   = (const float*)d_in[18];
  const float* ff1b   = (const float*)d_in[19];
  const float* ff2w   = (const float*)d_in[20];
  const float* ff2b   = (const float*)d_in[21];
  const float* ipw    = (const float*)d_in[22];
  const float* cw     = (const float*)d_in[23];
  const float* cb     = (const float*)d_in[24];
  const float* dtb    = (const float*)d_in[25];
  const float* Alog   = (const float*)d_in[26];
  const float* Dsk    = (const float*)d_in[27];
  const float* mnw    = (const float*)d_in[28];
  const float* outw   = (const float*)d_in[29];
  const float* rmsw   = (const float*)d_in[30];
  const float* olng   = (const float*)d_in[31];
  const float* olnb   = (const float*)d_in[32];

  float* ws = (float*)d_ws;
  const size_t MG = 1u << 20;
  // small region (< 1M floats)
  float* W1   = ws + 0;        // 16384
  float* W2   = ws + 16384;    // 65536
  float* SC   = ws + 81920;    // 512
  float* BQKV = ws + 82432;    // 49152
  float* KV   = ws + 131584;   // 65536
  float* KS   = ws + 197120;   // 2048
  float* DT   = ws + 199168;   // 65536
  float* DA   = ws + 264704;   // 65536
  float* CUM  = ws + 330240;   // 65536
  float* ACH  = ws + 395776;   // 2048
  float* PKV  = ws + 397824;   // 524288 (attn kv partials, live only within attn)
  float* PKS  = ws + 922112;   // 16384
  // big region R at 1M..~5.57M, time-multiplexed
  float* R    = ws + MG;
  float* OUT1 = R;                       // 4M  (gemm1 -> gemm2)
  float* QKV  = R;                       // 3M  (qkv -> attn)
  float* ATTN = R + 3 * MG;              // 1M
  float* MID  = R;                       // 2M  (ffn mid)
  float* ZX   = R;                       // 4.57M (in_proj -> gate)
  float* ECH  = ws + 5 * MG + 786432;    // 2M at 5.75M..7.75M (scan chunk states)
  float* H    = ws + 8 * MG;             // 1M, persistent residual
  float* ATMP = ws + 9 * MG;             // 1M, ln outs
  float* XC   = ws + 10 * MG;            // 2.56M
  float* Y    = ws + 12 * MG + 786432;   // 2M at 12.75M..14.75M
  float* out  = (float*)d_out;

  prep_k<<<513, 256, 0, stream>>>(w_in, b_in, c1w, bn1g, bn1b, c2w, bn2g, bn2b,
                                  wq, wk, wv, W1, W2, SC, BQKV);
  // fused (x@w_in -> conv1 -> bn -> gelu):  (32768x128)@(128x128)
  gemm_k<EPI_BNGELU, 64><<<dim3(512, 1), 256, 0, stream>>>(
      x, W1, OUT1, nullptr, SC, SC + 128, nullptr, nullptr, nullptr, 32768, 128, 128);
  // conv2 -> bn -> gelu -> H;  LN1 fused -> ATMP
  gemm_k<EPI_BNGELU_LN, 32><<<dim3(256, 1), 256, 0, stream>>>(
      OUT1, W2, H, nullptr, SC + 256, SC + 384, ln1g, ln1b, ATMP, 8192, 128, 512);
  // fused q|k|v projection, elu+1 on q,k
  gemm_k<EPI_QKV, 32><<<dim3(256, 3), 256, 0, stream>>>(
      ATMP, BQKV, QKV, nullptr, nullptr, nullptr, nullptr, nullptr, nullptr, 8192, 384, 128);
  attn_kv_part_k<<<512, 256, 0, stream>>>(QKV, PKV, PKS);
  attn_kv_red_k<<<64, 256, 0, stream>>>(PKV, PKS, KV, KS);
  attn_apply_k<<<8192, 128, 0, stream>>>(QKV, KV, KS, ATTN);
  // h += attn@wo + bo -> H;  LN2 fused -> ATMP
  gemm_k<EPI_RESBIAS_LN, 32><<<dim3(256, 1), 256, 0, stream>>>(
      ATTN, wo, H, H, bo, nullptr, ln2g, ln2b, ATMP, 8192, 128, 128);
  gemm_k<EPI_BIASGELU, 32><<<dim3(256, 2), 256, 0, stream>>>(
      ATMP, ff1w, MID, nullptr, ff1b, nullptr, nullptr, nullptr, nullptr, 8192, 256, 128);
  gemm_k<EPI_RESBIAS, 32><<<dim3(256, 1), 256, 0, stream>>>(
      MID, ff2w, H, H, ff2b, nullptr, nullptr, nullptr, nullptr, 8192, 128, 256);
  // in_proj: (8192x128)@(128x584)
  gemm_k<EPI_NONE, 32><<<dim3(256, 5), 256, 0, stream>>>(
      H, ipw, ZX, nullptr, nullptr, nullptr, nullptr, nullptr, nullptr, 8192, 584, 128);
  mamba_conv_k<<<8192, 320, 0, stream>>>(ZX, cw, cb, dtb, Alog, XC, DT, DA);
  scan_chunk_k<<<2048, 256, 0, stream>>>(XC, DT, DA, Dsk, Y, ECH, ACH, CUM);
  scan_fix_k<<<128, 1024, 0, stream>>>(XC, CUM, ECH, ACH, Y);
  gate_rms_k<<<8192, 256, 0, stream>>>(Y, ZX, mnw);
  // out-gemm: t = Y@outw; fused (t + H) -> RMS -> LN -> out
  gemm_k<EPI_FINAL, 32><<<dim3(256, 1), 256, 0, stream>>>(
      Y, outw, out, H, rmsw, nullptr, olng, olnb, nullptr, 8192, 128, 256);
  (void)in_sizes; (void)n_in; (void)out_size; (void)ws_size;
}

// Round 16
// 396.507 us; speedup vs baseline: 1.6305x; 1.0384x over previous
//
#include <hip/hip_runtime.h>
#include <cstdint>
#include <cstddef>

// Shapes
// B=16, L=16384, E=16, H=128, NH=4, DH=32, FF=256, D_STATE=32, HEADDIM=32
// D_INNER=256, NHEADS=8, CONV_DIM=320, DCONV=4, LC=512, ROWS=B*LC=8192

#define EPI_NONE 0
#define EPI_BNGELU 1
#define EPI_QKV 2
#define EPI_RESBIAS 3
#define EPI_BIASGELU 4
#define EPI_BNGELU_LN 5
#define EPI_RESBIAS_LN 6
#define EPI_FINAL 7

static __device__ __forceinline__ float gelu_f(float x) {
  float t = tanhf(0.7978845608028654f * (x + 0.044715f * x * x * x));
  return 0.5f * x * (1.0f + t);
}

// ---------------- prep: effective conv weights, BN folding, qkv pack ----------------
__global__ __launch_bounds__(256) void prep_k(
    const float* __restrict__ w_in, const float* __restrict__ b_in,
    const float* __restrict__ c1w, const float* __restrict__ bn1g,
    const float* __restrict__ bn1b, const float* __restrict__ c2w,
    const float* __restrict__ bn2g, const float* __restrict__ bn2b,
    const float* __restrict__ wq, const float* __restrict__ wk,
    const float* __restrict__ wv,
    float* __restrict__ W1, float* __restrict__ W2,
    float* __restrict__ sc, float* __restrict__ Bqkv) {
  int idx = blockIdx.x * 256 + threadIdx.x;
  const float inv = rsqrtf(1.0f + 1e-5f);
  if (idx < 16384) {
    int k = idx >> 7, c = idx & 127;
    int e = k & 15, i = k >> 4;
    float s = 0.f;
    #pragma unroll 4
    for (int cin = 0; cin < 128; ++cin)
      s += w_in[e * 128 + cin] * c1w[c * 1024 + cin * 8 + i];
    W1[idx] = s;
  } else if (idx < 16384 + 65536) {
    int j = idx - 16384;
    int k = j >> 7, c = j & 127;
    int i = k >> 7, cin = k & 127;
    W2[j] = c2w[c * 512 + cin * 4 + i];
  } else if (idx < 16384 + 65536 + 128) {
    int c = idx - (16384 + 65536);
    float b1 = 0.f;
    for (int cin = 0; cin < 128; ++cin) {
      float bi = b_in[cin];
      #pragma unroll
      for (int i = 0; i < 8; ++i) b1 += bi * c1w[c * 1024 + cin * 8 + i];
    }
    float s1 = bn1g[c] * inv;
    sc[c] = s1;
    sc[128 + c] = b1 * s1 + bn1b[c];
    sc[256 + c] = bn2g[c] * inv;
    sc[384 + c] = bn2b[c];
  } else {
    int j = idx - (16384 + 65536 + 128);
    if (j < 128 * 384) {
      int k = j / 384, n = j % 384;
      float v = (n < 128) ? wq[k * 128 + n]
              : (n < 256) ? wk[k * 128 + (n - 128)]
                          : wv[k * 128 + (n - 256)];
      Bqkv[j] = v;
    }
  }
}

// ---------------- generic fp32 GEMM, row-major, BM x 128 x BK=32, 256 thr ----------------
// BM in {16, 32, 64}. RT = BM/8 rows per thread. grid.x = M/BM, grid.y = ceil(N/128).
// As row stride 36 floats (144 B) keeps float4 LDS reads 16B-aligned.
// LN-fused epilogues (EPI_*_LN, EPI_FINAL) require N == BN == 128 (full row per block).
template <int EPI, int BM>
__global__ __launch_bounds__(256) void gemm_k(
    const float* __restrict__ A, const float* __restrict__ B,
    float* __restrict__ C, const float* __restrict__ Cres,
    const float* __restrict__ v0, const float* __restrict__ v1,
    const float* __restrict__ g, const float* __restrict__ bb,
    float* __restrict__ C2,
    int M, int N, int K) {
  constexpr int RT = BM / 8;
  constexpr int A4 = BM * 8;     // float4 count of the A tile
  __shared__ float As[BM][36];
  __shared__ float Bs[32][128];
  const int tid = threadIdx.x;
  const int row0 = blockIdx.x * BM;
  const int n0 = blockIdx.y * 128;
  const int tr = tid >> 5, tc = tid & 31;
  float acc[RT][4];
  #pragma unroll
  for (int i = 0; i < RT; ++i)
    for (int j = 0; j < 4; ++j) acc[i][j] = 0.f;

  for (int k0 = 0; k0 < K; k0 += 32) {
    #pragma unroll
    for (int i = 0; i < (A4 + 255) / 256; ++i) {
      int j = i * 256 + tid;
      if (A4 >= 256 || j < A4) {
        int m = j >> 3, k4 = (j & 7) << 2;
        const float4 av = *(const float4*)(A + (size_t)(row0 + m) * K + k0 + k4);
        *(float4*)&As[m][k4] = av;
      }
    }
    #pragma unroll
    for (int i = 0; i < 4; ++i) {
      int j = i * 256 + tid;
      int kk = j >> 5, c4 = (j & 31) << 2;
      float4 bv = make_float4(0.f, 0.f, 0.f, 0.f);
      if (n0 + c4 < N) bv = *(const float4*)(B + (size_t)(k0 + kk) * N + n0 + c4);
      *(float4*)&Bs[kk][c4] = bv;
    }
    __syncthreads();
    #pragma unroll
    for (int kk4 = 0; kk4 < 8; ++kk4) {
      float4 a4[RT];
      #pragma unroll
      for (int i = 0; i < RT; ++i)
        a4[i] = *(const float4*)&As[tr * RT + i][kk4 << 2];
      #pragma unroll
      for (int sub = 0; sub < 4; ++sub) {
        const float4 bv = *(const float4*)&Bs[(kk4 << 2) + sub][tc << 2];
        #pragma unroll
        for (int i = 0; i < RT; ++i) {
          float a = (sub == 0) ? a4[i].x : (sub == 1) ? a4[i].y
                  : (sub == 2) ? a4[i].z : a4[i].w;
          acc[i][0] = fmaf(a, bv.x, acc[i][0]);
          acc[i][1] = fmaf(a, bv.y, acc[i][1]);
          acc[i][2] = fmaf(a, bv.z, acc[i][2]);
          acc[i][3] = fmaf(a, bv.w, acc[i][3]);
        }
      }
    }
    __syncthreads();
  }

  int cc = n0 + (tc << 2);
  if (cc >= N) return;
  #pragma unroll
  for (int i = 0; i < RT; ++i) {
    int rr = row0 + tr * RT + i;
    float v[4];
    #pragma unroll
    for (int jj = 0; jj < 4; ++jj) {
      float x = acc[i][jj];
      if (EPI == EPI_BNGELU || EPI == EPI_BNGELU_LN)
        x = gelu_f(x * v0[cc + jj] + v1[cc + jj]);
      else if (EPI == EPI_QKV) { if (cc + jj < 256) x = (x > 0.f) ? x + 1.f : __expf(x); }
      else if (EPI == EPI_RESBIAS || EPI == EPI_RESBIAS_LN)
        x = Cres[(size_t)rr * N + cc + jj] + x + v0[cc + jj];
      else if (EPI == EPI_BIASGELU) x = gelu_f(x + v0[cc + jj]);
      else if (EPI == EPI_FINAL) x = x + Cres[(size_t)rr * N + cc + jj];
      v[jj] = x;
    }
    if (EPI != EPI_FINAL)
      *(float4*)(C + (size_t)rr * N + cc) = make_float4(v[0], v[1], v[2], v[3]);
    if (EPI == EPI_BNGELU_LN || EPI == EPI_RESBIAS_LN) {
      float s = v[0] + v[1] + v[2] + v[3];
      float q = v[0]*v[0] + v[1]*v[1] + v[2]*v[2] + v[3]*v[3];
      #pragma unroll
      for (int off = 1; off < 32; off <<= 1) {
        s += __shfl_xor(s, off);
        q += __shfl_xor(q, off);
      }
      float m = s * (1.f / 128.f);
      float var = q * (1.f / 128.f) - m * m;
      float ivr = rsqrtf(var + 1e-5f);
      float o[4];
      #pragma unroll
      for (int jj = 0; jj < 4; ++jj)
        o[jj] = (v[jj] - m) * ivr * g[cc + jj] + bb[cc + jj];
      *(float4*)(C2 + (size_t)rr * N + cc) = make_float4(o[0], o[1], o[2], o[3]);
    } else if (EPI == EPI_FINAL) {
      // RMS(128) with weight v0, then LN with g, bb -> C
      float q = v[0]*v[0] + v[1]*v[1] + v[2]*v[2] + v[3]*v[3];
      #pragma unroll
      for (int off = 1; off < 32; off <<= 1) q += __shfl_xor(q, off);
      float rs = rsqrtf(q * (1.f / 128.f) + 1e-6f);
      float r[4];
      #pragma unroll
      for (int jj = 0; jj < 4; ++jj) r[jj] = v[jj] * rs * v0[cc + jj];
      float s = r[0] + r[1] + r[2] + r[3];
      float q2 = r[0]*r[0] + r[1]*r[1] + r[2]*r[2] + r[3]*r[3];
      #pragma unroll
      for (int off = 1; off < 32; off <<= 1) {
        s += __shfl_xor(s, off);
        q2 += __shfl_xor(q2, off);
      }
      float m = s * (1.f / 128.f);
      float var = q2 * (1.f / 128.f) - m * m;
      float ivr = rsqrtf(var + 1e-5f);
      float o[4];
      #pragma unroll
      for (int jj = 0; jj < 4; ++jj)
        o[jj] = (r[jj] - m) * ivr * g[cc + jj] + bb[cc + jj];
      *(float4*)(C + (size_t)rr * N + cc) = make_float4(o[0], o[1], o[2], o[3]);
    }
  }
}

// ---- linear-attn phase 1: partial kv/ksum per (b,h,chunk of 64 rows) ----
__global__ __launch_bounds__(256) void attn_kv_part_k(
    const float* __restrict__ qkv, float* __restrict__ pkv, float* __restrict__ pks) {
  int bx = blockIdx.x;  // bh*8 + ch
  int bh = bx >> 3, ch = bx & 7;
  int b = bh >> 2, h = bh & 3;
  int t = threadIdx.x;
  int d = t >> 3, e4 = (t & 7) << 2;
  __shared__ float ks[8][32], vs[8][32];
  float a0 = 0, a1 = 0, a2 = 0, a3 = 0, ksa = 0;
  size_t base = (size_t)b * 512 * 384;
  int l0 = ch * 64;
  for (int lc = l0; lc < l0 + 64; lc += 8) {
    #pragma unroll
    for (int i = 0; i < 2; ++i) {
      int j = i * 256 + t;
      int rl = j >> 6, rem = j & 63, half = rem >> 5, col = rem & 31;
      float val = qkv[base + (size_t)(lc + rl) * 384 + 128 + half * 128 + h * 32 + col];
      if (half) vs[rl][col] = val; else ks[rl][col] = val;
    }
    __syncthreads();
    #pragma unroll
    for (int r = 0; r < 8; ++r) {
      float kd = ks[r][d];
      if ((t & 7) == 0) ksa += kd;
      a0 = fmaf(kd, vs[r][e4 + 0], a0);
      a1 = fmaf(kd, vs[r][e4 + 1], a1);
      a2 = fmaf(kd, vs[r][e4 + 2], a2);
      a3 = fmaf(kd, vs[r][e4 + 3], a3);
    }
    __syncthreads();
  }
  float* kvp = pkv + (size_t)bx * 1024 + d * 32 + e4;
  kvp[0] = a0; kvp[1] = a1; kvp[2] = a2; kvp[3] = a3;
  if ((t & 7) == 0) pks[bx * 32 + d] = ksa;
}

// ---- linear-attn phase 2: reduce 8 chunk partials -> kv[b,h], ksum[b,h] ----
__global__ __launch_bounds__(256) void attn_kv_red_k(
    const float* __restrict__ pkv, const float* __restrict__ pks,
    float* __restrict__ kv, float* __restrict__ ksum) {
  int bh = blockIdx.x;
  int t = threadIdx.x;
  float4 acc = make_float4(0.f, 0.f, 0.f, 0.f);
  #pragma unroll
  for (int ch = 0; ch < 8; ++ch) {
    const float4 v = *(const float4*)(pkv + ((size_t)(bh * 8 + ch)) * 1024 + t * 4);
    acc.x += v.x; acc.y += v.y; acc.z += v.z; acc.w += v.w;
  }
  *(float4*)(kv + (size_t)bh * 1024 + t * 4) = acc;
  if (t < 32) {
    float s = 0.f;
    #pragma unroll
    for (int ch = 0; ch < 8; ++ch) s += pks[(bh * 8 + ch) * 32 + t];
    ksum[bh * 32 + t] = s;
  }
}

// ---------------- linear-attn apply ----------------
__global__ __launch_bounds__(128) void attn_apply_k(
    const float* __restrict__ qkv, const float* __restrict__ kv,
    const float* __restrict__ ksum, float* __restrict__ attn) {
  int row = blockIdx.x;
  int t = threadIdx.x, h = t >> 5, e = t & 31;
  int b = row >> 9;
  const float* qr = qkv + (size_t)row * 384 + h * 32;
  const float* kvp = kv + (size_t)(b * 4 + h) * 1024;
  const float* ksp = ksum + (b * 4 + h) * 32;
  float num = 0.f, den = 0.f;
  #pragma unroll 8
  for (int d = 0; d < 32; ++d) {
    float qd = qr[d];
    num = fmaf(qd, kvp[d * 32 + e], num);
    den = fmaf(qd, ksp[d], den);
  }
  attn[(size_t)row * 128 + t] = num / (den + 1e-6f);
}

// -------- mamba depthwise causal conv + silu; dt softplus; dA = exp(dt*A) --------
__global__ __launch_bounds__(320) void mamba_conv_k(
    const float* __restrict__ zx, const float* __restrict__ cw,
    const float* __restrict__ cb, const float* __restrict__ dtb,
    const float* __restrict__ Alog,
    float* __restrict__ xc, float* __restrict__ dt, float* __restrict__ da) {
  int row = blockIdx.x;  // b*512 + l
  int c = threadIdx.x;   // 0..319
  int l = row & 511;
  float acc = cb[c];
  #pragma unroll
  for (int i = 0; i < 4; ++i) {
    int dl = i - 3;
    if (l + dl >= 0)
      acc += zx[(size_t)(row + dl) * 584 + 256 + c] * cw[c * 4 + i];
  }
  float s = acc / (1.f + __expf(-acc));  // silu
  xc[(size_t)row * 320 + c] = s;
  if (c < 8) {
    float r = zx[(size_t)row * 584 + 576 + c] + dtb[c];
    float dtv = fmaxf(r, 0.f) + log1pf(__expf(-fabsf(r)));  // softplus
    dt[(size_t)row * 8 + c] = dtv;
    float Ah = -__expf(Alog[c]);
    da[(size_t)row * 8 + c] = __expf(dtv * Ah);
  }
}

// ---------------- SSM scan: chunked parallel scan ----------------
__global__ __launch_bounds__(256) void scan_chunk_k(
    const float* __restrict__ xc, const float* __restrict__ dt,
    const float* __restrict__ da, const float* __restrict__ Dsk,
    float* __restrict__ y, float* __restrict__ ech,
    float* __restrict__ ach, float* __restrict__ cum) {
  int bx = blockIdx.x;  // h*256 + b*16 + c
  int h = bx >> 8, b = (bx >> 4) & 15, c = bx & 15;
  int t = threadIdx.x;
  int nh = t & 7, p = t >> 3;
  float Dh = Dsk[h];
  float h0 = 0.f, h1 = 0.f, h2 = 0.f, h3 = 0.f, cp = 1.f;
  size_t row = (size_t)b * 512 + c * 32;
  const float* dtp = dt + row * 8 + h;
  const float* dap = da + row * 8 + h;
  const float* xp = xc + row * 320 + h * 32 + p;
  const float* Bp = xc + row * 320 + 256 + nh * 4;
  const float* Cp = xc + row * 320 + 288 + nh * 4;
  float* yp = y + row * 256 + h * 32 + p;
  int bh = b * 8 + h;
  float* cpo = cum + (size_t)bh * 512 + c * 32;
  #pragma unroll 4
  for (int l = 0; l < 32; ++l) {
    float dtv = dtp[l * 8];
    float dav = dap[l * 8];
    float xs = xp[(size_t)l * 320];
    float4 Bq = *(const float4*)(Bp + (size_t)l * 320);
    float4 Cq = *(const float4*)(Cp + (size_t)l * 320);
    float ux = dtv * xs;
    h0 = fmaf(h0, dav, ux * Bq.x);
    h1 = fmaf(h1, dav, ux * Bq.y);
    h2 = fmaf(h2, dav, ux * Bq.z);
    h3 = fmaf(h3, dav, ux * Bq.w);
    float yv = Cq.x * h0;
    yv = fmaf(Cq.y, h1, yv);
    yv = fmaf(Cq.z, h2, yv);
    yv = fmaf(Cq.w, h3, yv);
    yv += __shfl_xor(yv, 1);
    yv += __shfl_xor(yv, 2);
    yv += __shfl_xor(yv, 4);
    cp *= dav;
    if (nh == 0) yp[(size_t)l * 256] = yv + Dh * xs;
    if (t == 0) cpo[l] = cp;
  }
  *(float4*)(ech + ((size_t)(bh * 16 + c)) * 1024 + p * 32 + nh * 4) =
      make_float4(h0, h1, h2, h3);
  if (t == 0) ach[bh * 16 + c] = cp;
}

// Phase BC: serial chunk-combine (16 steps) + correction.
__global__ __launch_bounds__(1024) void scan_fix_k(
    const float* __restrict__ xc, const float* __restrict__ cum,
    const float* __restrict__ ech, const float* __restrict__ ach,
    float* __restrict__ y) {
  int bh = blockIdx.x;
  int b = bh >> 3, h = bh & 7;
  int t = threadIdx.x;
  int pq = t >> 5, nq = t & 31;
  int lw = t >> 5, pp = t & 31;
  __shared__ float Hs[32][33];
  float Hreg = 0.f;
  const size_t row0 = (size_t)b * 512;
  for (int c = 0; c < 16; ++c) {
    Hs[pq][nq] = Hreg;
    __syncthreads();
    float e = ech[((size_t)(bh * 16 + c)) * 1024 + t];
    float a = ach[bh * 16 + c];
    Hreg = fmaf(Hreg, a, e);
    if (c) {
      int l = c * 32 + lw;
      size_t row = row0 + l;
      const float* Cr = xc + row * 320 + 288;
      float dot = 0.f;
      #pragma unroll 8
      for (int n = 0; n < 32; ++n) dot = fmaf(Cr[n], Hs[pp][n], dot);
      float cd = cum[(size_t)bh * 512 + l];
      y[row * 256 + h * 32 + pp] += cd * dot;
    }
    __syncthreads();
  }
}

// ---------------- y gating: y *= silu(zg); RMS(256) * mnorm_w ----------------
__global__ __launch_bounds__(256) void gate_rms_k(
    float* __restrict__ y, const float* __restrict__ zx, const float* __restrict__ mw) {
  int row = blockIdx.x;
  int c = threadIdx.x;
  float zg = zx[(size_t)row * 584 + c];
  float val = y[(size_t)row * 256 + c] * (zg / (1.f + __expf(-zg)));
  float sq = val * val;
  #pragma unroll
  for (int off = 1; off < 64; off <<= 1) sq += __shfl_xor(sq, off);
  __shared__ float ps[4];
  if ((c & 63) == 0) ps[c >> 6] = sq;
  __syncthreads();
  float tot = ps[0] + ps[1] + ps[2] + ps[3];
  y[(size_t)row * 256 + c] = val * rsqrtf(tot * (1.f / 256.f) + 1e-6f) * mw[c];
}

extern "C" void kernel_launch(void* const* d_in, const int* in_sizes, int n_in,
                              void* d_out, int out_size, void* d_ws, size_t ws_size,
                              hipStream_t stream) {
  const float* x      = (const float*)d_in[0];
  const float* w_in   = (const float*)d_in[1];
  const float* b_in   = (const float*)d_in[2];
  const float* c1w    = (const float*)d_in[3];
  const float* bn1g   = (const float*)d_in[4];
  const float* bn1b   = (const float*)d_in[5];
  const float* c2w    = (const float*)d_in[6];
  const float* bn2g   = (const float*)d_in[7];
  const float* bn2b   = (const float*)d_in[8];
  const float* ln1g   = (const float*)d_in[9];
  const float* ln1b   = (const float*)d_in[10];
  const float* wq     = (const float*)d_in[11];
  const float* wk     = (const float*)d_in[12];
  const float* wv     = (const float*)d_in[13];
  const float* wo     = (const float*)d_in[14];
  const float* bo     = (const float*)d_in[15];
  const float* ln2g   = (const float*)d_in[16];
  const float* ln2b   = (const float*)d_in[17];
  const float* ff1w   = (const float*)d_in[18];
  const float* ff1b   = (const float*)d_in[19];
  const float* ff2w   = (const float*)d_in[20];
  const float* ff2b   = (const float*)d_in[21];
  const float* ipw    = (const float*)d_in[22];
  const float* cw     = (const float*)d_in[23];
  const float* cb     = (const float*)d_in[24];
  const float* dtb    = (const float*)d_in[25];
  const float* Alog   = (const float*)d_in[26];
  const float* Dsk    = (const float*)d_in[27];
  const float* mnw    = (const float*)d_in[28];
  const float* outw   = (const float*)d_in[29];
  const float* rmsw   = (const float*)d_in[30];
  const float* olng   = (const float*)d_in[31];
  const float* olnb   = (const float*)d_in[32];

  float* ws = (float*)d_ws;
  const size_t MG = 1u << 20;
  // small region (< 1M floats)
  float* W1   = ws + 0;        // 16384
  float* W2   = ws + 16384;    // 65536
  float* SC   = ws + 81920;    // 512
  float* BQKV = ws + 82432;    // 49152
  float* KV   = ws + 131584;   // 65536
  float* KS   = ws + 197120;   // 2048
  float* DT   = ws + 199168;   // 65536
  float* DA   = ws + 264704;   // 65536
  float* CUM  = ws + 330240;   // 65536
  float* ACH  = ws + 395776;   // 2048
  float* PKV  = ws + 397824;   // 524288 (attn kv partials, live only within attn)
  float* PKS  = ws + 922112;   // 16384
  // big region R at 1M..~5.57M, time-multiplexed
  float* R    = ws + MG;
  float* OUT1 = R;                       // 4M  (gemm1 -> gemm2)
  float* QKV  = R;                       // 3M  (qkv -> attn)
  float* ATTN = R + 3 * MG;              // 1M
  float* MID  = R;                       // 2M  (ffn mid)
  float* ZX   = R;                       // 4.57M (in_proj -> gate)
  float* ECH  = ws + 5 * MG + 786432;    // 2M at 5.75M..7.75M (scan chunk states)
  float* H    = ws + 8 * MG;             // 1M, persistent residual
  float* ATMP = ws + 9 * MG;             // 1M, ln outs
  float* XC   = ws + 10 * MG;            // 2.56M
  float* Y    = ws + 12 * MG + 786432;   // 2M at 12.75M..14.75M
  float* out  = (float*)d_out;

  prep_k<<<513, 256, 0, stream>>>(w_in, b_in, c1w, bn1g, bn1b, c2w, bn2g, bn2b,
                                  wq, wk, wv, W1, W2, SC, BQKV);
  // fused (x@w_in -> conv1 -> bn -> gelu):  (32768x128)@(128x128)
  gemm_k<EPI_BNGELU, 32><<<dim3(1024, 1), 256, 0, stream>>>(
      x, W1, OUT1, nullptr, SC, SC + 128, nullptr, nullptr, nullptr, 32768, 128, 128);
  // conv2 -> bn -> gelu -> H;  LN1 fused -> ATMP
  gemm_k<EPI_BNGELU_LN, 16><<<dim3(512, 1), 256, 0, stream>>>(
      OUT1, W2, H, nullptr, SC + 256, SC + 384, ln1g, ln1b, ATMP, 8192, 128, 512);
  // fused q|k|v projection, elu+1 on q,k
  gemm_k<EPI_QKV, 16><<<dim3(512, 3), 256, 0, stream>>>(
      ATMP, BQKV, QKV, nullptr, nullptr, nullptr, nullptr, nullptr, nullptr, 8192, 384, 128);
  attn_kv_part_k<<<512, 256, 0, stream>>>(QKV, PKV, PKS);
  attn_kv_red_k<<<64, 256, 0, stream>>>(PKV, PKS, KV, KS);
  attn_apply_k<<<8192, 128, 0, stream>>>(QKV, KV, KS, ATTN);
  // h += attn@wo + bo -> H;  LN2 fused -> ATMP
  gemm_k<EPI_RESBIAS_LN, 16><<<dim3(512, 1), 256, 0, stream>>>(
      ATTN, wo, H, H, bo, nullptr, ln2g, ln2b, ATMP, 8192, 128, 128);
  gemm_k<EPI_BIASGELU, 16><<<dim3(512, 2), 256, 0, stream>>>(
      ATMP, ff1w, MID, nullptr, ff1b, nullptr, nullptr, nullptr, nullptr, 8192, 256, 128);
  gemm_k<EPI_RESBIAS, 16><<<dim3(512, 1), 256, 0, stream>>>(
      MID, ff2w, H, H, ff2b, nullptr, nullptr, nullptr, nullptr, 8192, 128, 256);
  // in_proj: (8192x128)@(128x584)
  gemm_k<EPI_NONE, 16><<<dim3(512, 5), 256, 0, stream>>>(
      H, ipw, ZX, nullptr, nullptr, nullptr, nullptr, nullptr, nullptr, 8192, 584, 128);
  mamba_conv_k<<<8192, 320, 0, stream>>>(ZX, cw, cb, dtb, Alog, XC, DT, DA);
  scan_chunk_k<<<2048, 256, 0, stream>>>(XC, DT, DA, Dsk, Y, ECH, ACH, CUM);
  scan_fix_k<<<128, 1024, 0, stream>>>(XC, CUM, ECH, ACH, Y);
  gate_rms_k<<<8192, 256, 0, stream>>>(Y, ZX, mnw);
  // out-gemm: t = Y@outw; fused (t + H) -> RMS -> LN -> out
  gemm_k<EPI_FINAL, 16><<<dim3(512, 1), 256, 0, stream>>>(
      Y, outw, out, H, rmsw, nullptr, olng, olnb, nullptr, 8192, 128, 256);
  (void)in_sizes; (void)n_in; (void)out_size; (void)ws_size;
}